// Round 8
// baseline (662.289 us; speedup 1.0000x reference)
//
#include <hip/hip_runtime.h>
#include <hip/hip_bf16.h>

typedef __hip_bfloat16 bf16;
typedef __attribute__((ext_vector_type(8))) short bf16x8;   // 8 bf16 = 4 VGPRs
typedef __attribute__((ext_vector_type(4))) float f32x4;

#define TOK    1024
#define DIM    96
#define HIDN   384
#define HEADS  8
#define DH     768
#define INNER  6144
#define SEQ    512
#define NDEPTH 5
#define EPSLN  1e-5f
#define QSCALE 0.125f

#define MFMA16(a, b, c) __builtin_amdgcn_mfma_f32_16x16x32_bf16((a), (b), (c), 0, 0, 0)

__device__ __forceinline__ float b2f(bf16 v) { return __bfloat162float(v); }
__device__ __forceinline__ bf16  f2b(float v) { return __float2bfloat16(v); }

// Load element i from an external input buffer: f==1 -> bf16, f==0 -> fp32.
__device__ __forceinline__ float gload(const void* p, size_t i, int f) {
  return f ? b2f(((const bf16*)p)[i]) : ((const float*)p)[i];
}
__device__ __forceinline__ const char* gptr(const void* base, size_t off, int f) {
  return (const char*)base + off * (size_t)(f ? 2 : 4);
}

// pack 8 fp32 -> 8 bf16 (two float4 registers) into a uint4
__device__ __forceinline__ uint4 pack8(float4 u0, float4 u1) {
  alignas(16) unsigned short o[8];
  bf16 t;
  t = f2b(u0.x); o[0] = *(unsigned short*)&t;
  t = f2b(u0.y); o[1] = *(unsigned short*)&t;
  t = f2b(u0.z); o[2] = *(unsigned short*)&t;
  t = f2b(u0.w); o[3] = *(unsigned short*)&t;
  t = f2b(u1.x); o[4] = *(unsigned short*)&t;
  t = f2b(u1.y); o[5] = *(unsigned short*)&t;
  t = f2b(u1.z); o[6] = *(unsigned short*)&t;
  t = f2b(u1.w); o[7] = *(unsigned short*)&t;
  return *(const uint4*)o;
}

// ---------------- dtype detector (bf16 vs fp32 external buffers) ------------
__global__ __launch_bounds__(256) void detect_kernel(const void* xraw, int* flag) {
  __shared__ int cnt[256];
  int t = threadIdx.x;
  const unsigned short* u = (const unsigned short*)xraw;
  int c = 0;
  #pragma unroll
  for (int i = 0; i < 4; i++) {
    unsigned short h = u[2 * (t * 4 + i)];
    int e = (h >> 7) & 0xFF;
    if (e >= 87 && e <= 132) c++;
  }
  cnt[t] = c;
  __syncthreads();
  for (int s = 128; s > 0; s >>= 1) {
    if (t < s) cnt[t] += cnt[t + s];
    __syncthreads();
  }
  if (t == 0) *flag = (cnt[0] > 700) ? 1 : 0;
}

// ---- all weight transposes in ONE launch: grid 6180 x 256 ------------------
// b < 5760: Wo [15][6144][96];  b < 5940: W1 [10][96][384];  else W2 [10][384][96].
// Body: [bz][R][C] -> bf16 [bz][C][R], vectorized loads/stores (R%32==0, C%4==0).
__global__ __launch_bounds__(256) void wtrans_all_kernel(
    const void* __restrict__ Wo, const void* __restrict__ W1,
    const void* __restrict__ W2, bf16* __restrict__ woT,
    bf16* __restrict__ w1T, bf16* __restrict__ w2T,
    const int* __restrict__ flagp) {
  __shared__ float tile[32][65];
  int f = *flagp;
  int b = blockIdx.x;
  const void* src; bf16* dst; int R, C, bx, by, bz;
  if (b < 5760) {
    src = Wo; dst = woT; R = INNER; C = DIM;
    bz = b / 384; int rem = b % 384; bx = rem & 1; by = rem >> 1;
  } else if (b < 5940) {
    int idx = b - 5760;
    src = W1; dst = w1T; R = DIM; C = HIDN;
    bx = idx % 6; by = (idx / 6) % 3; bz = idx / 18;
  } else {
    int idx = b - 5940;
    src = W2; dst = w2T; R = HIDN; C = DIM;
    bx = idx & 1; by = (idx >> 1) % 12; bz = idx / 24;
  }
  int t = threadIdx.x;
  int c0 = bx * 64, r0 = by * 32;
  size_t bb = (size_t)bz * R * C;
  int ty = t >> 4, tx = t & 15;
  #pragma unroll
  for (int half = 0; half < 2; half++) {
    int r = r0 + ty + half * 16;
    int c = c0 + tx * 4;
    if (c < C) {
      size_t idx = bb + (size_t)r * C + c;
      float v0, v1, v2, v3;
      if (f) {
        uint2 u = *(const uint2*)((const unsigned short*)src + idx);
        v0 = __uint_as_float((u.x & 0xffffu) << 16);
        v1 = __uint_as_float(u.x & 0xffff0000u);
        v2 = __uint_as_float((u.y & 0xffffu) << 16);
        v3 = __uint_as_float(u.y & 0xffff0000u);
      } else {
        float4 v = *(const float4*)((const float*)src + idx);
        v0 = v.x; v1 = v.y; v2 = v.z; v3 = v.w;
      }
      tile[ty + half * 16][tx * 4 + 0] = v0;
      tile[ty + half * 16][tx * 4 + 1] = v1;
      tile[ty + half * 16][tx * 4 + 2] = v2;
      tile[ty + half * 16][tx * 4 + 3] = v3;
    }
  }
  __syncthreads();
  int cc = c0 + (t >> 2), rseg = (t & 3) * 8;
  if (cc < C) {
    int cs = cc - c0;
    alignas(16) unsigned short o[8];
    #pragma unroll
    for (int j = 0; j < 8; j++) {
      bf16 tv = f2b(tile[rseg + j][cs]);
      o[j] = *(unsigned short*)&tv;
    }
    *(uint4*)&dst[bb + (size_t)cc * R + r0 + rseg] = *(const uint4*)o;
  }
}

// =================== MFMA GEMM body — BT form (B is [N][K]) =================
// A/B sources may be fp32 (converted to bf16 during LDS staging) or bf16.
// Block 256 = 4 waves (2x2). If Cf != null, store raw fp32 partials there.
template <int WM>
__device__ __forceinline__ void gemm_bt_body(
    const void* __restrict__ A, int aF32, int lda,
    const void* __restrict__ Bt, int bF32, int ldb,
    int m0, int n0, int kbeg, int kend, int Mtot, int N,
    float alpha, bf16* __restrict__ Cb, float* __restrict__ Cf, int ldc) {
  constexpr int TM = WM * 32;
  __shared__ bf16 As[TM][40];
  __shared__ bf16 Bs[128][40];
  int t = threadIdx.x;
  int lane = t & 63;
  int wave = t >> 6;
  int wm = (wave >> 1) * (WM * 16), wn = (wave & 1) * 64;
  f32x4 acc[WM][4];
  #pragma unroll
  for (int i = 0; i < WM; i++)
    #pragma unroll
    for (int j = 0; j < 4; j++) acc[i][j] = (f32x4){0.f, 0.f, 0.f, 0.f};

  int arow = t >> 2, aseg = (t & 3) * 8;

  for (int kb = kbeg; kb < kend; kb += 32) {
    #pragma unroll
    for (int i = 0; i < (TM + 63) / 64; i++) {
      int rr = arow + i * 64;
      if ((TM % 64 == 0) || rr < TM) {
        int gm = min(m0 + rr, Mtot - 1);
        size_t idx = (size_t)gm * lda + kb + aseg;
        if (aF32) {
          const float* Af = (const float*)A;
          float4 u0 = *(const float4*)(Af + idx);
          float4 u1 = *(const float4*)(Af + idx + 4);
          *(uint4*)&As[rr][aseg] = pack8(u0, u1);
        } else {
          *(uint4*)&As[rr][aseg] = *(const uint4*)((const bf16*)A + idx);
        }
      }
    }
    #pragma unroll
    for (int i = 0; i < 2; i++) {
      int r = arow + i * 64;
      int gn = n0 + r;
      if (gn < N) {
        size_t idx = (size_t)gn * ldb + kb + aseg;
        if (bF32) {
          const float* Bf = (const float*)Bt;
          float4 u0 = *(const float4*)(Bf + idx);
          float4 u1 = *(const float4*)(Bf + idx + 4);
          *(uint4*)&Bs[r][aseg] = pack8(u0, u1);
        } else {
          *(uint4*)&Bs[r][aseg] = *(const uint4*)((const bf16*)Bt + idx);
        }
      } else {
        uint4 zz = {0, 0, 0, 0};
        *(uint4*)&Bs[r][aseg] = zz;
      }
    }
    __syncthreads();
    int fm = lane & 15, fq = (lane >> 4) * 8;
    bf16x8 af[WM], bfv[4];
    #pragma unroll
    for (int i = 0; i < WM; i++)
      af[i] = *(const bf16x8*)&As[wm + i * 16 + fm][fq];
    #pragma unroll
    for (int j = 0; j < 4; j++)
      bfv[j] = *(const bf16x8*)&Bs[wn + j * 16 + fm][fq];
    #pragma unroll
    for (int i = 0; i < WM; i++)
      #pragma unroll
      for (int j = 0; j < 4; j++)
        acc[i][j] = MFMA16(af[i], bfv[j], acc[i][j]);
    __syncthreads();
  }
  int col = lane & 15, rq = (lane >> 4) * 4;
  #pragma unroll
  for (int j = 0; j < 4; j++) {
    int gn = n0 + wn + j * 16 + col;
    if (gn >= N) continue;
    #pragma unroll
    for (int i = 0; i < WM; i++) {
      #pragma unroll
      for (int r = 0; r < 4; r++) {
        int gm = m0 + wm + i * 16 + rq + r;
        if (gm >= Mtot) continue;
        if (Cf) Cf[(size_t)gm * ldc + gn] = acc[i][j][r];
        else    Cb[(size_t)gm * ldc + gn] = f2b(acc[i][j][r] * alpha);
      }
    }
  }
}

// ---- precompute Mt/Gt partials: grid (12, 1, 240) --------------------------
// x = ks*3 + mtile (K-split 4 x m-split 3); z<120 -> Mt, z>=120 -> Gt.
// fp32 partials -> P[ks][z][96][96]; summed/scaled/converted by cvtcast.
__global__ __launch_bounds__(256) void mtgt_kernel(
    const void* __restrict__ WqE, const void* __restrict__ WkE,
    const void* __restrict__ WvE, const bf16* __restrict__ woT,
    float* __restrict__ P, const int* __restrict__ flagp) {
  int f = *flagp;
  int z = blockIdx.z;
  int ks = blockIdx.x / 3, mt = blockIdx.x % 3;
  bool isM = z < 120;
  int zz = isM ? z : z - 120;
  int L = zz >> 3, h = zz & 7;
  size_t wo = (size_t)L * DIM * INNER + (size_t)h * DH;
  const void* A  = isM ? (const void*)((const char*)WkE + wo * (f ? 2 : 4))
                       : (const void*)(woT + wo);
  const void* Bt = isM ? (const void*)((const char*)WqE + wo * (f ? 2 : 4))
                       : (const void*)((const char*)WvE + wo * (f ? 2 : 4));
  int aF32 = isM ? !f : 0;
  int bF32 = !f;
  float* Cf = P + ((size_t)ks * 240 + z) * DIM * DIM;
  gemm_bt_body<1>(A, aF32, INNER, Bt, bF32, INNER,
                  mt * 32, 0, ks * (DH / 4), (ks + 1) * (DH / 4), DIM, DIM,
                  1.f, nullptr, Cf, DIM);
}

// ---- per-row LayerNorm helper: one wave, row of 96 (v1 valid for lane<32) --
__device__ __forceinline__ void ln_row_vals(float v0, float v1in, int lane,
    const char* g, int f, float& o0, float& o1) {
  float v1 = (lane < 32) ? v1in : 0.f;
  float s = v0 + v1;
  #pragma unroll
  for (int off = 32; off > 0; off >>= 1) s += __shfl_xor(s, off);
  float mu = s * (1.f / 96.f);
  float d0 = v0 - mu;
  float d1 = (lane < 32) ? (v1 - mu) : 0.f;
  float q = d0 * d0 + d1 * d1;
  #pragma unroll
  for (int off = 32; off > 0; off >>= 1) q += __shfl_xor(q, off);
  float rstd = rsqrtf(q * (1.f / 96.f) + EPSLN);
  o0 = d0 * rstd * (gload(g, lane, f) + 1.f);
  o1 = (lane < 32) ? (d1 * rstd * (gload(g, 64 + lane, f) + 1.f)) : 0.f;
}

__device__ __forceinline__ void store_hn(bf16* hn, bf16* hnT, int row, int lane,
                                         float o0, float o1) {
  size_t base = (size_t)row * DIM;
  bf16* hT = hnT + (size_t)(row >> 9) * DIM * SEQ;
  int ss = row & (SEQ - 1);
  hn[base + lane] = f2b(o0);
  hT[(size_t)lane * SEQ + ss] = f2b(o0);
  if (lane < 32) {
    hn[base + 64 + lane] = f2b(o1);
    hT[(size_t)(64 + lane) * SEQ + ss] = f2b(o1);
  }
}

// ---- fused: sum K-split partials -> Mt/Gt  AND  input cast + LN0 -----------
// grid (2160 + 256) x 256: blocks <2160 convert; blocks >=2160 do castln.
__global__ __launch_bounds__(256) void cvtcast_kernel(
    const float* __restrict__ P, bf16* __restrict__ Mt, bf16* __restrict__ Gt,
    const void* __restrict__ in_x, float* __restrict__ x,
    bf16* __restrict__ hn, bf16* __restrict__ hnT,
    const void* __restrict__ gb, const int* __restrict__ flagp) {
  if (blockIdx.x < 2160) {
    const int n = 240 * DIM * DIM;
    int i0 = (blockIdx.x * 256 + threadIdx.x) * 4;
    if (i0 >= n) return;
    int z = i0 / (DIM * DIM);
    bool isM = z < 120;
    float alpha = isM ? QSCALE : 1.f;
    float4 a = *(const float4*)(P + i0);
    float4 b = *(const float4*)(P + n + i0);
    float4 c = *(const float4*)(P + 2 * (size_t)n + i0);
    float4 d = *(const float4*)(P + 3 * (size_t)n + i0);
    bf16* out = isM ? (Mt + i0) : (Gt + (size_t)i0 - (size_t)120 * DIM * DIM);
    alignas(8) unsigned short o[4];
    bf16 t;
    t = f2b(((a.x + b.x) + (c.x + d.x)) * alpha); o[0] = *(unsigned short*)&t;
    t = f2b(((a.y + b.y) + (c.y + d.y)) * alpha); o[1] = *(unsigned short*)&t;
    t = f2b(((a.z + b.z) + (c.z + d.z)) * alpha); o[2] = *(unsigned short*)&t;
    t = f2b(((a.w + b.w) + (c.w + d.w)) * alpha); o[3] = *(unsigned short*)&t;
    *(uint2*)out = *(const uint2*)o;
  } else {
    int f = *flagp;
    int wave = threadIdx.x >> 6, lane = threadIdx.x & 63;
    int row = (blockIdx.x - 2160) * 4 + wave;
    size_t base = (size_t)row * DIM;
    float v0 = gload(in_x, base + lane, f);
    float v1 = (lane < 32) ? gload(in_x, base + 64 + lane, f) : 0.f;
    x[base + lane] = v0;
    if (lane < 32) x[base + 64 + lane] = v1;
    float o0, o1;
    ln_row_vals(v0, v1, lane, gptr(gb, 0, f), f, o0, o1);
    store_hn(hn, hnT, row, lane, o0, o1);
  }
}

// ---- standalone LN (attn -> attn transition): grid 256 x 256t --------------
__global__ __launch_bounds__(256) void ln_kernel(
    const float* __restrict__ x, bf16* __restrict__ hn, bf16* __restrict__ hnT,
    const void* __restrict__ gb, size_t goff, const int* __restrict__ flagp) {
  int f = *flagp;
  int wave = threadIdx.x >> 6, lane = threadIdx.x & 63;
  int row = blockIdx.x * 4 + wave;
  size_t base = (size_t)row * DIM;
  float v0 = x[base + lane];
  float v1 = (lane < 32) ? x[base + 64 + lane] : 0.f;
  float o0, o1;
  ln_row_vals(v0, v1, lane, gptr(gb, goff, f), f, o0, o1);
  store_hn(hn, hnT, row, lane, o0, o1);
}

// ============== fused attention v4: 8 waves, halved critical path ===========
// grid (16 q-tiles, 16 z=b*8+h) x 512 threads.
// t + S + softmax + (P@hn)@Gt^T, B operands direct from L2-resident global.
__global__ __launch_bounds__(512) void fattn4_kernel(
    const bf16* __restrict__ hn,    // [1024][96]
    const bf16* __restrict__ hnT,   // [2][96][512]
    const bf16* __restrict__ MtL,   // [8][96][96]
    const bf16* __restrict__ GtL,   // [8][96][96]
    float* __restrict__ x) {
  __shared__ bf16 tP[32][520];
  __shared__ bf16 Zs[32][104];
  __shared__ float red[2][8][32];
  int tid = threadIdx.x, lane = tid & 63, wave = tid >> 6;  // wave 0..7
  int fm = lane & 15, fq = (lane >> 4) * 8;
  int col = lane & 15, rq = (lane >> 4) * 4;
  int z = blockIdx.y, b = z >> 3, h = z & 7;
  int m0 = blockIdx.x * 32;
  const bf16* hnB = hn + (size_t)b * SEQ * DIM;
  const bf16* hTB = hnT + (size_t)b * DIM * SEQ;
  const bf16* MtH = MtL + (size_t)h * DIM * DIM;
  const bf16* GtH = GtL + (size_t)h * DIM * DIM;

  // ---- stage 1: t = hn_tile[32x96] @ Mt^T; waves 0..5, 2 n-frags each ----
  if (wave < 6) {
    int mA = wave & 1, nb = wave >> 1;     // n-frags {nb, nb+3}
    f32x4 a0 = (f32x4){0.f, 0.f, 0.f, 0.f}, a1 = a0;
    #pragma unroll
    for (int kb = 0; kb < 96; kb += 32) {
      bf16x8 af = *(const bf16x8*)(hnB + (size_t)(m0 + mA * 16 + fm) * DIM + kb + fq);
      bf16x8 b0 = *(const bf16x8*)(MtH + (size_t)(nb * 16 + fm) * DIM + kb + fq);
      bf16x8 b1 = *(const bf16x8*)(MtH + (size_t)((nb + 3) * 16 + fm) * DIM + kb + fq);
      a0 = MFMA16(af, b0, a0);
      a1 = MFMA16(af, b1, a1);
    }
    #pragma unroll
    for (int r = 0; r < 4; r++) {
      Zs[mA * 16 + rq + r][nb * 16 + col] = f2b(a0[r]);
      Zs[mA * 16 + rq + r][(nb + 3) * 16 + col] = f2b(a1[r]);
    }
  }
  __syncthreads();

  // ---- stage 2: S = t @ hn^T (32 x 512); wave covers 64 cols ----
  f32x4 acc2[2][4];
  #pragma unroll
  for (int i = 0; i < 2; i++)
    #pragma unroll
    for (int j = 0; j < 4; j++) acc2[i][j] = (f32x4){0.f, 0.f, 0.f, 0.f};
  #pragma unroll
  for (int kb = 0; kb < 96; kb += 32) {
    bf16x8 af0 = *(const bf16x8*)&Zs[fm][kb + fq];
    bf16x8 af1 = *(const bf16x8*)&Zs[16 + fm][kb + fq];
    bf16x8 bv[4];
    #pragma unroll
    for (int j = 0; j < 4; j++)
      bv[j] = *(const bf16x8*)(hnB + (size_t)(wave * 64 + j * 16 + fm) * DIM + kb + fq);
    #pragma unroll
    for (int j = 0; j < 4; j++) {
      acc2[0][j] = MFMA16(af0, bv[j], acc2[0][j]);
      acc2[1][j] = MFMA16(af1, bv[j], acc2[1][j]);
    }
  }

  // ---- softmax over 512 cols (8 wave-partials) ----
  float rmax[2][4];
  #pragma unroll
  for (int i = 0; i < 2; i++)
    #pragma unroll
    for (int r = 0; r < 4; r++) {
      float m = -1e30f;
      #pragma unroll
      for (int j = 0; j < 4; j++) m = fmaxf(m, acc2[i][j][r]);
      rmax[i][r] = m;
    }
  #pragma unroll
  for (int s = 1; s < 16; s <<= 1)
    #pragma unroll
    for (int i = 0; i < 2; i++)
      #pragma unroll
      for (int r = 0; r < 4; r++)
        rmax[i][r] = fmaxf(rmax[i][r], __shfl_xor(rmax[i][r], s));
  if (col == 0)
    #pragma unroll
    for (int i = 0; i < 2; i++)
      #pragma unroll
      for (int r = 0; r < 4; r++) red[0][wave][i * 16 + rq + r] = rmax[i][r];
  __syncthreads();
  float rsum[2][4];
  #pragma unroll
  for (int i = 0; i < 2; i++)
    #pragma unroll
    for (int r = 0; r < 4; r++) {
      int row = i * 16 + rq + r;
      float gm = red[0][0][row];
      #pragma unroll
      for (int q = 1; q < 8; q++) gm = fmaxf(gm, red[0][q][row]);
      float s = 0.f;
      #pragma unroll
      for (int j = 0; j < 4; j++) {
        float e = __expf(acc2[i][j][r] - gm);
        acc2[i][j][r] = e;
        s += e;
      }
      rsum[i][r] = s;
    }
  #pragma unroll
  for (int s = 1; s < 16; s <<= 1)
    #pragma unroll
    for (int i = 0; i < 2; i++)
      #pragma unroll
      for (int r = 0; r < 4; r++)
        rsum[i][r] += __shfl_xor(rsum[i][r], s);
  if (col == 0)
    #pragma unroll
    for (int i = 0; i < 2; i++)
      #pragma unroll
      for (int r = 0; r < 4; r++) red[1][wave][i * 16 + rq + r] = rsum[i][r];
  __syncthreads();

  // each wave writes its own normalized 64-col P chunk
  #pragma unroll
  for (int i = 0; i < 2; i++)
    #pragma unroll
    for (int r = 0; r < 4; r++) {
      int row = i * 16 + rq + r;
      float tot = red[1][0][row];
      #pragma unroll
      for (int q = 1; q < 8; q++) tot += red[1][q][row];
      float inv = 1.f / tot;
      #pragma unroll
      for (int j = 0; j < 4; j++)
        tP[row][wave * 64 + j * 16 + col] = f2b(acc2[i][j][r] * inv);
    }
  __syncthreads();

  // ---- stage 3a: Z = P @ hnT^T (32 x 96), K = 512 ----
  f32x4 z0 = (f32x4){0.f, 0.f, 0.f, 0.f}, z1 = z0;
  if (wave < 4) {
    int n = wave;
    #pragma unroll 4
    for (int kb = 0; kb < 512; kb += 32) {
      bf16x8 bv = *(const bf16x8*)(hTB + (size_t)(n * 16 + fm) * SEQ + kb + fq);
      bf16x8 af0 = *(const bf16x8*)&tP[fm][kb + fq];
      bf16x8 af1 = *(const bf16x8*)&tP[16 + fm][kb + fq];
      z0 = MFMA16(af0, bv, z0);
      z1 = MFMA16(af1, bv, z1);
    }
    #pragma unroll
    for (int r = 0; r < 4; r++) {
      Zs[rq + r][n * 16 + col] = f2b(z0[r]);
      Zs[16 + rq + r][n * 16 + col] = f2b(z1[r]);
    }
  } else {
    int mA = wave & 1, n = (wave >> 1) + 2;   // wave 4,5 -> n=4; 6,7 -> n=5
    #pragma unroll 4
    for (int kb = 0; kb < 512; kb += 32) {
      bf16x8 bv = *(const bf16x8*)(hTB + (size_t)(n * 16 + fm) * SEQ + kb + fq);
      bf16x8 af = *(const bf16x8*)&tP[mA * 16 + fm][kb + fq];
      z0 = MFMA16(af, bv, z0);
    }
    #pragma unroll
    for (int r = 0; r < 4; r++)
      Zs[mA * 16 + rq + r][n * 16 + col] = f2b(z0[r]);
  }
  __syncthreads();

  // ---- stage 3b: O = Z @ Gt^T (32 x 96); waves 0..5, 2 n-frags each ----
  if (wave < 6) {
    int mA = wave & 1, nb = wave >> 1;
    f32x4 o0 = (f32x4){0.f, 0.f, 0.f, 0.f}, o1 = o0;
    #pragma unroll
    for (int kb = 0; kb < 96; kb += 32) {
      bf16x8 af = *(const bf16x8*)&Zs[mA * 16 + fm][kb + fq];
      bf16x8 b0 = *(const bf16x8*)(GtH + (size_t)(nb * 16 + fm) * DIM + kb + fq);
      bf16x8 b1 = *(const bf16x8*)(GtH + (size_t)((nb + 3) * 16 + fm) * DIM + kb + fq);
      o0 = MFMA16(af, b0, o0);
      o1 = MFMA16(af, b1, o1);
    }
    #pragma unroll
    for (int r = 0; r < 4; r++) {
      int gr = b * SEQ + m0 + mA * 16 + rq + r;
      atomicAdd(x + (size_t)gr * DIM + nb * 16 + col, o0[r]);
      atomicAdd(x + (size_t)gr * DIM + (nb + 3) * 16 + col, o1[r]);
    }
  }
}

// ====== fused MLP (8 waves): [gmid-LN] + LN + GEMM1 + GELU + GEMM2 + res ====
// grid (32) x 512 threads; each block owns 32 rows. LN epilogue:
// lnmode 1 -> hn/hnT with gamma(lngb+lngoff); lnmode 2 -> final LN to dout.
__global__ __launch_bounds__(512) void fmlp_kernel(
    float* __restrict__ X,
    const void* __restrict__ gmidb, size_t gmidoff, int useMid,
    const void* __restrict__ gmb, size_t gmoff,
    const bf16* __restrict__ w1T,   // [384][96]
    const void* __restrict__ b1b, size_t b1off,
    const bf16* __restrict__ w2T,   // [96][384]
    const void* __restrict__ b2b, size_t b2off,
    int lnmode, const void* __restrict__ lngb, size_t lngoff,
    bf16* __restrict__ hn, bf16* __restrict__ hnT, void* __restrict__ dout,
    const int* __restrict__ flagp) {
  __shared__ float X1s[32][96];   // residual basis, updated in-place by GEMM2
  __shared__ bf16 As[32][104];
  __shared__ bf16 Hs[32][392];
  int f = *flagp;
  int tid = threadIdx.x, lane = tid & 63, wave = tid >> 6;  // 0..7
  int fm = lane & 15, fq = (lane >> 4) * 8;
  int col = lane & 15, rq = (lane >> 4) * 4;
  int m0 = blockIdx.x * 32;
  const char* gm = gptr(gmb, gmoff, f);
  float gm0 = gload(gm, lane, f) + 1.f;
  float gm1 = (lane < 32) ? (gload(gm, 64 + lane, f) + 1.f) : 0.f;
  float gd0 = 1.f, gd1 = 1.f;
  if (useMid) {
    const char* gmid = gptr(gmidb, gmidoff, f);
    gd0 = gload(gmid, lane, f) + 1.f;
    gd1 = (lane < 32) ? (gload(gmid, 64 + lane, f) + 1.f) : 0.f;
  }
  for (int r = wave; r < 32; r += 8) {
    const float* xr = X + (size_t)(m0 + r) * DIM;
    float v0 = xr[lane];
    float v1 = (lane < 32) ? xr[64 + lane] : 0.f;
    if (useMid) {
      float s = v0 + v1;
      #pragma unroll
      for (int off = 32; off > 0; off >>= 1) s += __shfl_xor(s, off);
      float mu = s * (1.f / 96.f);
      float d0 = v0 - mu;
      float d1 = (lane < 32) ? (v1 - mu) : 0.f;
      float q = d0 * d0 + d1 * d1;
      #pragma unroll
      for (int off = 32; off > 0; off >>= 1) q += __shfl_xor(q, off);
      float rstd = rsqrtf(q * (1.f / 96.f) + EPSLN);
      v0 = d0 * rstd * gd0;
      v1 = (lane < 32) ? (d1 * rstd * gd1) : 0.f;
    }
    X1s[r][lane] = v0;
    if (lane < 32) X1s[r][64 + lane] = v1;
    float s = v0 + v1;
    #pragma unroll
    for (int off = 32; off > 0; off >>= 1) s += __shfl_xor(s, off);
    float mu = s * (1.f / 96.f);
    float d0 = v0 - mu;
    float d1 = (lane < 32) ? (v1 - mu) : 0.f;
    float q = d0 * d0 + d1 * d1;
    #pragma unroll
    for (int off = 32; off > 0; off >>= 1) q += __shfl_xor(q, off);
    float rstd = rsqrtf(q * (1.f / 96.f) + EPSLN);
    As[r][lane] = f2b(d0 * rstd * gm0);
    if (lane < 32) As[r][64 + lane] = f2b(d1 * rstd * gm1);
  }
  __syncthreads();

  // ---- GEMM1: [32x96] @ W1 -> [32x384]; wave = (m, 96-col chunk) ----
  int mw = wave & 1, nh = wave >> 1;     // nh in 0..3: cols [nh*96, nh*96+96)
  f32x4 acc1[6];
  #pragma unroll
  for (int j = 0; j < 6; j++) acc1[j] = (f32x4){0.f, 0.f, 0.f, 0.f};
  #pragma unroll
  for (int kb = 0; kb < 96; kb += 32) {
    bf16x8 af = *(const bf16x8*)&As[mw * 16 + fm][kb + fq];
    #pragma unroll
    for (int j = 0; j < 6; j++) {
      bf16x8 bv = *(const bf16x8*)(w1T + (size_t)(nh * 96 + j * 16 + fm) * DIM + kb + fq);
      acc1[j] = MFMA16(af, bv, acc1[j]);
    }
  }
  const char* b1p = gptr(b1b, b1off, f);
  #pragma unroll
  for (int j = 0; j < 6; j++) {
    int gn = nh * 96 + j * 16 + col;
    float bv = gload(b1p, gn, f);
    #pragma unroll
    for (int r = 0; r < 4; r++) {
      float v = acc1[j][r] + bv;
      v = 0.5f * v * (1.f + erff(v * 0.70710678118f));
      Hs[mw * 16 + rq + r][gn] = f2b(v);
    }
  }
  __syncthreads();

  // ---- GEMM2: [32x384] @ W2 -> [32x96]; waves 0..5, 2 n-frags each ----
  // Updates X1s in-place (residual + out + bias) and stores to global X.
  if (wave < 6) {
    int mA = wave & 1, nb = wave >> 1;
    f32x4 o0 = (f32x4){0.f, 0.f, 0.f, 0.f}, o1 = o0;
    #pragma unroll 4
    for (int kb = 0; kb < 384; kb += 32) {
      bf16x8 af = *(const bf16x8*)&Hs[mA * 16 + fm][kb + fq];
      bf16x8 b0 = *(const bf16x8*)(w2T + (size_t)(nb * 16 + fm) * HIDN + kb + fq);
      bf16x8 b1 = *(const bf16x8*)(w2T + (size_t)((nb + 3) * 16 + fm) * HIDN + kb + fq);
      o0 = MFMA16(af, b0, o0);
      o1 = MFMA16(af, b1, o1);
    }
    const char* b2p = gptr(b2b, b2off, f);
    float bb0 = gload(b2p, nb * 16 + col, f);
    float bb1 = gload(b2p, (nb + 3) * 16 + col, f);
    #pragma unroll
    for (int r = 0; r < 4; r++) {
      int row = mA * 16 + rq + r;
      int gmr = m0 + row;
      float nv0 = X1s[row][nb * 16 + col] + o0[r] + bb0;
      float nv1 = X1s[row][(nb + 3) * 16 + col] + o1[r] + bb1;
      X[(size_t)gmr * DIM + nb * 16 + col] = nv0;
      X[(size_t)gmr * DIM + (nb + 3) * 16 + col] = nv1;
      X1s[row][nb * 16 + col] = nv0;
      X1s[row][(nb + 3) * 16 + col] = nv1;
    }
  }
  __syncthreads();

  // ---- fused LN epilogue over this block's 32 rows (reads X1s, not X) ----
  const char* lg = gptr(lngb, lngoff, f);
  for (int r = wave; r < 32; r += 8) {
    int row = m0 + r;
    size_t base = (size_t)row * DIM;
    float v0 = X1s[r][lane];
    float v1 = (lane < 32) ? X1s[r][64 + lane] : 0.f;
    float o0, o1;
    ln_row_vals(v0, v1, lane, lg, f, o0, o1);
    if (lnmode == 1) {
      store_hn(hn, hnT, row, lane, o0, o1);
    } else {
      if (!f) {
        ((float*)dout)[base + lane] = o0;
        if (lane < 32) ((float*)dout)[base + 64 + lane] = o1;
      } else {
        ((bf16*)dout)[base + lane] = f2b(o0);
        if (lane < 32) ((bf16*)dout)[base + 64 + lane] = f2b(o1);
      }
    }
  }
}

// ---------------- host-side orchestration ----------------
extern "C" void kernel_launch(void* const* d_in, const int* in_sizes, int n_in,
                              void* d_out, int out_size, void* d_ws, size_t ws_size,
                              hipStream_t stream) {
  const void* in_x    = d_in[0];
  const void* gam_a   = d_in[1];
  const void* Wq      = d_in[2];
  const void* Wk      = d_in[3];
  const void* Wv      = d_in[4];
  const void* Wo      = d_in[5];
  const void* gam_m   = d_in[6];
  const void* W1      = d_in[7];
  const void* b1      = d_in[8];
  const void* W2      = d_in[9];
  const void* b2      = d_in[10];
  const void* gam_mid = d_in[11];
  const void* gam_fin = d_in[12];

  char* wsb = (char*)d_ws;
  size_t off = 0;
  auto carve = [&](size_t bytes) {
    char* p = wsb + off;
    off += (bytes + 255) & ~(size_t)255;
    return p;
  };
  int*   flag = (int*)carve(256);
  float* x    = (float*)carve((size_t)TOK * DIM * 4);
  bf16*  hn   = (bf16*)carve((size_t)TOK * DIM * 2);
  bf16*  hnT  = (bf16*)carve((size_t)2 * DIM * SEQ * 2);
  const size_t WSZ = (size_t)15 * DIM * INNER;   // per big weight, elements
  bf16*  woT  = (bf16*)carve(WSZ * 2);
  bf16*  w1T  = (bf16*)carve((size_t)10 * DIM * HIDN * 2);
  bf16*  w2T  = (bf16*)carve((size_t)10 * DIM * HIDN * 2);
  bf16*  Mt   = (bf16*)carve((size_t)120 * DIM * DIM * 2);
  bf16*  Gt   = (bf16*)carve((size_t)120 * DIM * DIM * 2);
  float* MtP  = (float*)carve((size_t)4 * 240 * DIM * DIM * 4);

  detect_kernel<<<dim3(1), dim3(256), 0, stream>>>(in_x, flag);

  // ---- once-per-call weight prep (4 dispatches total) ----
  wtrans_all_kernel<<<dim3(6180), dim3(256), 0, stream>>>(
      Wo, W1, W2, woT, w1T, w2T, flag);
  // Mt/Gt: K-split x4, m-split x3 -> 2880 blocks of fp32 partials.
  mtgt_kernel<<<dim3(12, 1, 240), dim3(256), 0, stream>>>(
      Wq, Wk, Wv, woT, MtP, flag);
  // fused: partial-sum/convert -> Mt/Gt  +  input cast + LN0 -> x, hn, hnT
  cvtcast_kernel<<<dim3(2160 + 256), dim3(256), 0, stream>>>(
      MtP, Mt, Gt, in_x, x, hn, hnT, gam_a, flag);

  auto attn = [&](int d, int j) {
    size_t gi = ((size_t)d * 3 + j);
    fattn4_kernel<<<dim3(16, 16), dim3(512), 0, stream>>>(
        hn, hnT, Mt + gi * 8 * DIM * DIM, Gt + gi * 8 * DIM * DIM, x);
  };

  for (int d = 0; d < NDEPTH; d++) {
    bool last = (d == NDEPTH - 1);
    attn(d, 0);
    // mlp0 + fused LN(gam_a[d,1]) -> hn/hnT for attn1
    fmlp_kernel<<<dim3(32), dim3(512), 0, stream>>>(
        x, nullptr, 0, 0,
        gam_m, (size_t)(d * 2 + 0) * DIM,
        w1T + (size_t)(d * 2 + 0) * DIM * HIDN, b1, (size_t)(d * 2 + 0) * HIDN,
        w2T + (size_t)(d * 2 + 0) * DIM * HIDN, b2, (size_t)(d * 2 + 0) * DIM,
        1, gam_a, (size_t)(d * 3 + 1) * DIM, hn, hnT, nullptr, flag);
    attn(d, 1);
    ln_kernel<<<dim3(TOK / 4), dim3(256), 0, stream>>>(
        x, hn, hnT, gam_a, (size_t)(d * 3 + 2) * DIM, flag);
    attn(d, 2);
    // mlp1 (includes bare mid-LN) + fused LN: next gam_a[.,0] or final -> dout
    fmlp_kernel<<<dim3(32), dim3(512), 0, stream>>>(
        x, gam_mid, (size_t)d * DIM, 1,
        gam_m, (size_t)(d * 2 + 1) * DIM,
        w1T + (size_t)(d * 2 + 1) * DIM * HIDN, b1, (size_t)(d * 2 + 1) * HIDN,
        w2T + (size_t)(d * 2 + 1) * DIM * HIDN, b2, (size_t)(d * 2 + 1) * DIM,
        last ? 2 : 1, last ? gam_fin : gam_a,
        last ? (size_t)0 : (size_t)((d + 1) * 3) * DIM,
        hn, hnT, d_out, flag);
  }
}

// Round 9
// 646.783 us; speedup vs baseline: 1.0240x; 1.0240x over previous
//
#include <hip/hip_runtime.h>
#include <hip/hip_bf16.h>

typedef __hip_bfloat16 bf16;
typedef __attribute__((ext_vector_type(8))) short bf16x8;   // 8 bf16 = 4 VGPRs
typedef __attribute__((ext_vector_type(4))) float f32x4;

#define TOK    1024
#define DIM    96
#define HIDN   384
#define HEADS  8
#define DH     768
#define INNER  6144
#define SEQ    512
#define NDEPTH 5
#define EPSLN  1e-5f
#define QSCALE 0.125f

#define MFMA16(a, b, c) __builtin_amdgcn_mfma_f32_16x16x32_bf16((a), (b), (c), 0, 0, 0)

__device__ __forceinline__ float b2f(bf16 v) { return __bfloat162float(v); }
__device__ __forceinline__ bf16  f2b(float v) { return __float2bfloat16(v); }

// Load element i from an external input buffer: f==1 -> bf16, f==0 -> fp32.
__device__ __forceinline__ float gload(const void* p, size_t i, int f) {
  return f ? b2f(((const bf16*)p)[i]) : ((const float*)p)[i];
}
__device__ __forceinline__ const char* gptr(const void* base, size_t off, int f) {
  return (const char*)base + off * (size_t)(f ? 2 : 4);
}

// pack 8 fp32 -> 8 bf16 (two float4 registers) into a uint4
__device__ __forceinline__ uint4 pack8(float4 u0, float4 u1) {
  alignas(16) unsigned short o[8];
  bf16 t;
  t = f2b(u0.x); o[0] = *(unsigned short*)&t;
  t = f2b(u0.y); o[1] = *(unsigned short*)&t;
  t = f2b(u0.z); o[2] = *(unsigned short*)&t;
  t = f2b(u0.w); o[3] = *(unsigned short*)&t;
  t = f2b(u1.x); o[4] = *(unsigned short*)&t;
  t = f2b(u1.y); o[5] = *(unsigned short*)&t;
  t = f2b(u1.z); o[6] = *(unsigned short*)&t;
  t = f2b(u1.w); o[7] = *(unsigned short*)&t;
  return *(const uint4*)o;
}

// ---------------- dtype detector (bf16 vs fp32 external buffers) ------------
__global__ __launch_bounds__(256) void detect_kernel(const void* xraw, int* flag) {
  __shared__ int cnt[256];
  int t = threadIdx.x;
  const unsigned short* u = (const unsigned short*)xraw;
  int c = 0;
  #pragma unroll
  for (int i = 0; i < 4; i++) {
    unsigned short h = u[2 * (t * 4 + i)];
    int e = (h >> 7) & 0xFF;
    if (e >= 87 && e <= 132) c++;
  }
  cnt[t] = c;
  __syncthreads();
  for (int s = 128; s > 0; s >>= 1) {
    if (t < s) cnt[t] += cnt[t + s];
    __syncthreads();
  }
  if (t == 0) *flag = (cnt[0] > 700) ? 1 : 0;
}

// ---- all weight transposes in ONE launch: grid 6180 x 256 ------------------
// b < 5760: Wo [15][6144][96];  b < 5940: W1 [10][96][384];  else W2 [10][384][96].
__global__ __launch_bounds__(256) void wtrans_all_kernel(
    const void* __restrict__ Wo, const void* __restrict__ W1,
    const void* __restrict__ W2, bf16* __restrict__ woT,
    bf16* __restrict__ w1T, bf16* __restrict__ w2T,
    const int* __restrict__ flagp) {
  __shared__ float tile[32][65];
  int f = *flagp;
  int b = blockIdx.x;
  const void* src; bf16* dst; int R, C, bx, by, bz;
  if (b < 5760) {
    src = Wo; dst = woT; R = INNER; C = DIM;
    bz = b / 384; int rem = b % 384; bx = rem & 1; by = rem >> 1;
  } else if (b < 5940) {
    int idx = b - 5760;
    src = W1; dst = w1T; R = DIM; C = HIDN;
    bx = idx % 6; by = (idx / 6) % 3; bz = idx / 18;
  } else {
    int idx = b - 5940;
    src = W2; dst = w2T; R = HIDN; C = DIM;
    bx = idx & 1; by = (idx >> 1) % 12; bz = idx / 24;
  }
  int t = threadIdx.x;
  int c0 = bx * 64, r0 = by * 32;
  size_t bb = (size_t)bz * R * C;
  int ty = t >> 4, tx = t & 15;
  #pragma unroll
  for (int half = 0; half < 2; half++) {
    int r = r0 + ty + half * 16;
    int c = c0 + tx * 4;
    if (c < C) {
      size_t idx = bb + (size_t)r * C + c;
      float v0, v1, v2, v3;
      if (f) {
        uint2 u = *(const uint2*)((const unsigned short*)src + idx);
        v0 = __uint_as_float((u.x & 0xffffu) << 16);
        v1 = __uint_as_float(u.x & 0xffff0000u);
        v2 = __uint_as_float((u.y & 0xffffu) << 16);
        v3 = __uint_as_float(u.y & 0xffff0000u);
      } else {
        float4 v = *(const float4*)((const float*)src + idx);
        v0 = v.x; v1 = v.y; v2 = v.z; v3 = v.w;
      }
      tile[ty + half * 16][tx * 4 + 0] = v0;
      tile[ty + half * 16][tx * 4 + 1] = v1;
      tile[ty + half * 16][tx * 4 + 2] = v2;
      tile[ty + half * 16][tx * 4 + 3] = v3;
    }
  }
  __syncthreads();
  int cc = c0 + (t >> 2), rseg = (t & 3) * 8;
  if (cc < C) {
    int cs = cc - c0;
    alignas(16) unsigned short o[8];
    #pragma unroll
    for (int j = 0; j < 8; j++) {
      bf16 tv = f2b(tile[rseg + j][cs]);
      o[j] = *(unsigned short*)&tv;
    }
    *(uint4*)&dst[bb + (size_t)cc * R + r0 + rseg] = *(const uint4*)o;
  }
}

// =================== MFMA GEMM body — BT form (B is [N][K]) =================
// A/B sources may be fp32 (converted to bf16 during LDS staging) or bf16.
// Block 256 = 4 waves (2x2). If Cf != null, store raw fp32 partials there.
template <int WM>
__device__ __forceinline__ void gemm_bt_body(
    const void* __restrict__ A, int aF32, int lda,
    const void* __restrict__ Bt, int bF32, int ldb,
    int m0, int n0, int kbeg, int kend, int Mtot, int N,
    float alpha, bf16* __restrict__ Cb, float* __restrict__ Cf, int ldc) {
  constexpr int TM = WM * 32;
  __shared__ bf16 As[TM][40];
  __shared__ bf16 Bs[128][40];
  int t = threadIdx.x;
  int lane = t & 63;
  int wave = t >> 6;
  int wm = (wave >> 1) * (WM * 16), wn = (wave & 1) * 64;
  f32x4 acc[WM][4];
  #pragma unroll
  for (int i = 0; i < WM; i++)
    #pragma unroll
    for (int j = 0; j < 4; j++) acc[i][j] = (f32x4){0.f, 0.f, 0.f, 0.f};

  int arow = t >> 2, aseg = (t & 3) * 8;

  for (int kb = kbeg; kb < kend; kb += 32) {
    #pragma unroll
    for (int i = 0; i < (TM + 63) / 64; i++) {
      int rr = arow + i * 64;
      if ((TM % 64 == 0) || rr < TM) {
        int gm = min(m0 + rr, Mtot - 1);
        size_t idx = (size_t)gm * lda + kb + aseg;
        if (aF32) {
          const float* Af = (const float*)A;
          float4 u0 = *(const float4*)(Af + idx);
          float4 u1 = *(const float4*)(Af + idx + 4);
          *(uint4*)&As[rr][aseg] = pack8(u0, u1);
        } else {
          *(uint4*)&As[rr][aseg] = *(const uint4*)((const bf16*)A + idx);
        }
      }
    }
    #pragma unroll
    for (int i = 0; i < 2; i++) {
      int r = arow + i * 64;
      int gn = n0 + r;
      if (gn < N) {
        size_t idx = (size_t)gn * ldb + kb + aseg;
        if (bF32) {
          const float* Bf = (const float*)Bt;
          float4 u0 = *(const float4*)(Bf + idx);
          float4 u1 = *(const float4*)(Bf + idx + 4);
          *(uint4*)&Bs[r][aseg] = pack8(u0, u1);
        } else {
          *(uint4*)&Bs[r][aseg] = *(const uint4*)((const bf16*)Bt + idx);
        }
      } else {
        uint4 zz = {0, 0, 0, 0};
        *(uint4*)&Bs[r][aseg] = zz;
      }
    }
    __syncthreads();
    int fm = lane & 15, fq = (lane >> 4) * 8;
    bf16x8 af[WM], bfv[4];
    #pragma unroll
    for (int i = 0; i < WM; i++)
      af[i] = *(const bf16x8*)&As[wm + i * 16 + fm][fq];
    #pragma unroll
    for (int j = 0; j < 4; j++)
      bfv[j] = *(const bf16x8*)&Bs[wn + j * 16 + fm][fq];
    #pragma unroll
    for (int i = 0; i < WM; i++)
      #pragma unroll
      for (int j = 0; j < 4; j++)
        acc[i][j] = MFMA16(af[i], bfv[j], acc[i][j]);
    __syncthreads();
  }
  int col = lane & 15, rq = (lane >> 4) * 4;
  #pragma unroll
  for (int j = 0; j < 4; j++) {
    int gn = n0 + wn + j * 16 + col;
    if (gn >= N) continue;
    #pragma unroll
    for (int i = 0; i < WM; i++) {
      #pragma unroll
      for (int r = 0; r < 4; r++) {
        int gm = m0 + wm + i * 16 + rq + r;
        if (gm >= Mtot) continue;
        if (Cf) Cf[(size_t)gm * ldc + gn] = acc[i][j][r];
        else    Cb[(size_t)gm * ldc + gn] = f2b(acc[i][j][r] * alpha);
      }
    }
  }
}

// ---- precompute Mt/Gt partials: grid (6, 1, 240) ---------------------------
// x = ks*3 + mtile (K-split 2 x m-split 3); z<120 -> Mt, z>=120 -> Gt.
// fp32 partials -> P[ks][z][96][96]; summed/scaled/converted by cvtcast.
__global__ __launch_bounds__(256) void mtgt_kernel(
    const void* __restrict__ WqE, const void* __restrict__ WkE,
    const void* __restrict__ WvE, const bf16* __restrict__ woT,
    float* __restrict__ P, const int* __restrict__ flagp) {
  int f = *flagp;
  int z = blockIdx.z;
  int ks = blockIdx.x / 3, mt = blockIdx.x % 3;
  bool isM = z < 120;
  int zz = isM ? z : z - 120;
  int L = zz >> 3, h = zz & 7;
  size_t wo = (size_t)L * DIM * INNER + (size_t)h * DH;
  const void* A  = isM ? (const void*)((const char*)WkE + wo * (f ? 2 : 4))
                       : (const void*)(woT + wo);
  const void* Bt = isM ? (const void*)((const char*)WqE + wo * (f ? 2 : 4))
                       : (const void*)((const char*)WvE + wo * (f ? 2 : 4));
  int aF32 = isM ? !f : 0;
  int bF32 = !f;
  float* Cf = P + ((size_t)ks * 240 + z) * DIM * DIM;
  gemm_bt_body<1>(A, aF32, INNER, Bt, bF32, INNER,
                  mt * 32, 0, ks * (DH / 2), (ks + 1) * (DH / 2), DIM, DIM,
                  1.f, nullptr, Cf, DIM);
}

// ---- per-row LayerNorm helper: one wave, row of 96 (v1 valid for lane<32) --
__device__ __forceinline__ void ln_row_vals(float v0, float v1in, int lane,
    const char* g, int f, float& o0, float& o1) {
  float v1 = (lane < 32) ? v1in : 0.f;
  float s = v0 + v1;
  #pragma unroll
  for (int off = 32; off > 0; off >>= 1) s += __shfl_xor(s, off);
  float mu = s * (1.f / 96.f);
  float d0 = v0 - mu;
  float d1 = (lane < 32) ? (v1 - mu) : 0.f;
  float q = d0 * d0 + d1 * d1;
  #pragma unroll
  for (int off = 32; off > 0; off >>= 1) q += __shfl_xor(q, off);
  float rstd = rsqrtf(q * (1.f / 96.f) + EPSLN);
  o0 = d0 * rstd * (gload(g, lane, f) + 1.f);
  o1 = (lane < 32) ? (d1 * rstd * (gload(g, 64 + lane, f) + 1.f)) : 0.f;
}

__device__ __forceinline__ void store_hn(bf16* hn, bf16* hnT, int row, int lane,
                                         float o0, float o1) {
  size_t base = (size_t)row * DIM;
  bf16* hT = hnT + (size_t)(row >> 9) * DIM * SEQ;
  int ss = row & (SEQ - 1);
  hn[base + lane] = f2b(o0);
  hT[(size_t)lane * SEQ + ss] = f2b(o0);
  if (lane < 32) {
    hn[base + 64 + lane] = f2b(o1);
    hT[(size_t)(64 + lane) * SEQ + ss] = f2b(o1);
  }
}

// ---- fused: sum K-split partials -> Mt/Gt  AND  input cast + LN0 -----------
// grid (2160 + 256) x 256: blocks <2160 convert; blocks >=2160 do castln.
__global__ __launch_bounds__(256) void cvtcast_kernel(
    const float* __restrict__ P, bf16* __restrict__ Mt, bf16* __restrict__ Gt,
    const void* __restrict__ in_x, float* __restrict__ x,
    bf16* __restrict__ hn, bf16* __restrict__ hnT,
    const void* __restrict__ gb, const int* __restrict__ flagp) {
  if (blockIdx.x < 2160) {
    const int n = 240 * DIM * DIM;
    int i0 = (blockIdx.x * 256 + threadIdx.x) * 4;
    if (i0 >= n) return;
    int z = i0 / (DIM * DIM);
    bool isM = z < 120;
    float alpha = isM ? QSCALE : 1.f;
    float4 a = *(const float4*)(P + i0);
    float4 b = *(const float4*)(P + n + i0);
    bf16* out = isM ? (Mt + i0) : (Gt + (size_t)i0 - (size_t)120 * DIM * DIM);
    alignas(8) unsigned short o[4];
    bf16 t;
    t = f2b((a.x + b.x) * alpha); o[0] = *(unsigned short*)&t;
    t = f2b((a.y + b.y) * alpha); o[1] = *(unsigned short*)&t;
    t = f2b((a.z + b.z) * alpha); o[2] = *(unsigned short*)&t;
    t = f2b((a.w + b.w) * alpha); o[3] = *(unsigned short*)&t;
    *(uint2*)out = *(const uint2*)o;
  } else {
    int f = *flagp;
    int wave = threadIdx.x >> 6, lane = threadIdx.x & 63;
    int row = (blockIdx.x - 2160) * 4 + wave;
    size_t base = (size_t)row * DIM;
    float v0 = gload(in_x, base + lane, f);
    float v1 = (lane < 32) ? gload(in_x, base + 64 + lane, f) : 0.f;
    x[base + lane] = v0;
    if (lane < 32) x[base + 64 + lane] = v1;
    float o0, o1;
    ln_row_vals(v0, v1, lane, gptr(gb, 0, f), f, o0, o1);
    store_hn(hn, hnT, row, lane, o0, o1);
  }
}

// ---- standalone LN (attn -> attn transition): grid 256 x 256t --------------
__global__ __launch_bounds__(256) void ln_kernel(
    const float* __restrict__ x, bf16* __restrict__ hn, bf16* __restrict__ hnT,
    const void* __restrict__ gb, size_t goff, const int* __restrict__ flagp) {
  int f = *flagp;
  int wave = threadIdx.x >> 6, lane = threadIdx.x & 63;
  int row = blockIdx.x * 4 + wave;
  size_t base = (size_t)row * DIM;
  float v0 = x[base + lane];
  float v1 = (lane < 32) ? x[base + 64 + lane] : 0.f;
  float o0, o1;
  ln_row_vals(v0, v1, lane, gptr(gb, goff, f), f, o0, o1);
  store_hn(hn, hnT, row, lane, o0, o1);
}

// ============== fused attention v5: 16-row q-tiles, 2 blocks/CU =============
// grid (32 q-tiles, 16 z=b*8+h) x 512 threads (8 waves).
// t + S + softmax + (P@hn)@Gt^T, B operands direct from L2-resident global.
__global__ __launch_bounds__(512) void fattn5_kernel(
    const bf16* __restrict__ hn,    // [1024][96]
    const bf16* __restrict__ hnT,   // [2][96][512]
    const bf16* __restrict__ MtL,   // [8][96][96]
    const bf16* __restrict__ GtL,   // [8][96][96]
    float* __restrict__ x) {
  __shared__ bf16 tP[16][520];
  __shared__ bf16 Zs[16][104];
  __shared__ float red[2][8][16];
  int tid = threadIdx.x, lane = tid & 63, wave = tid >> 6;  // wave 0..7
  int fm = lane & 15, fq = (lane >> 4) * 8;
  int col = lane & 15, rq = (lane >> 4) * 4;
  int z = blockIdx.y, b = z >> 3, h = z & 7;
  int m0 = blockIdx.x * 16;
  const bf16* hnB = hn + (size_t)b * SEQ * DIM;
  const bf16* hTB = hnT + (size_t)b * DIM * SEQ;
  const bf16* MtH = MtL + (size_t)h * DIM * DIM;
  const bf16* GtH = GtL + (size_t)h * DIM * DIM;

  // ---- stage 1: t = hn_tile[16x96] @ Mt^T; waves 0..5, one n-frag each ----
  if (wave < 6) {
    int n = wave;
    f32x4 a0 = (f32x4){0.f, 0.f, 0.f, 0.f};
    #pragma unroll
    for (int kb = 0; kb < 96; kb += 32) {
      bf16x8 af = *(const bf16x8*)(hnB + (size_t)(m0 + fm) * DIM + kb + fq);
      bf16x8 bv = *(const bf16x8*)(MtH + (size_t)(n * 16 + fm) * DIM + kb + fq);
      a0 = MFMA16(af, bv, a0);
    }
    #pragma unroll
    for (int r = 0; r < 4; r++)
      Zs[rq + r][n * 16 + col] = f2b(a0[r]);
  }
  __syncthreads();

  // ---- stage 2: S = t @ hn^T (16 x 512); wave covers 64 cols ----
  f32x4 acc2[4];
  #pragma unroll
  for (int j = 0; j < 4; j++) acc2[j] = (f32x4){0.f, 0.f, 0.f, 0.f};
  #pragma unroll
  for (int kb = 0; kb < 96; kb += 32) {
    bf16x8 af = *(const bf16x8*)&Zs[fm][kb + fq];
    bf16x8 bv[4];
    #pragma unroll
    for (int j = 0; j < 4; j++)
      bv[j] = *(const bf16x8*)(hnB + (size_t)(wave * 64 + j * 16 + fm) * DIM + kb + fq);
    #pragma unroll
    for (int j = 0; j < 4; j++)
      acc2[j] = MFMA16(af, bv[j], acc2[j]);
  }

  // ---- softmax over 512 cols (8 wave-partials) ----
  float rmax[4];
  #pragma unroll
  for (int r = 0; r < 4; r++) {
    float m = -1e30f;
    #pragma unroll
    for (int j = 0; j < 4; j++) m = fmaxf(m, acc2[j][r]);
    rmax[r] = m;
  }
  #pragma unroll
  for (int s = 1; s < 16; s <<= 1)
    #pragma unroll
    for (int r = 0; r < 4; r++)
      rmax[r] = fmaxf(rmax[r], __shfl_xor(rmax[r], s));
  if (col == 0)
    #pragma unroll
    for (int r = 0; r < 4; r++) red[0][wave][rq + r] = rmax[r];
  __syncthreads();
  float rsum[4];
  #pragma unroll
  for (int r = 0; r < 4; r++) {
    int row = rq + r;
    float gm = red[0][0][row];
    #pragma unroll
    for (int q = 1; q < 8; q++) gm = fmaxf(gm, red[0][q][row]);
    float s = 0.f;
    #pragma unroll
    for (int j = 0; j < 4; j++) {
      float e = __expf(acc2[j][r] - gm);
      acc2[j][r] = e;
      s += e;
    }
    rsum[r] = s;
  }
  #pragma unroll
  for (int s = 1; s < 16; s <<= 1)
    #pragma unroll
    for (int r = 0; r < 4; r++)
      rsum[r] += __shfl_xor(rsum[r], s);
  if (col == 0)
    #pragma unroll
    for (int r = 0; r < 4; r++) red[1][wave][rq + r] = rsum[r];
  __syncthreads();

  // each wave writes its own normalized 64-col P chunk
  #pragma unroll
  for (int r = 0; r < 4; r++) {
    int row = rq + r;
    float tot = red[1][0][row];
    #pragma unroll
    for (int q = 1; q < 8; q++) tot += red[1][q][row];
    float inv = 1.f / tot;
    #pragma unroll
    for (int j = 0; j < 4; j++)
      tP[row][wave * 64 + j * 16 + col] = f2b(acc2[j][r] * inv);
  }
  __syncthreads();

  // ---- stage 3a: Z = P @ hnT^T (16 x 96), K = 512; waves 0..5 -------------
  if (wave < 6) {
    int n = wave;
    f32x4 z0 = (f32x4){0.f, 0.f, 0.f, 0.f};
    #pragma unroll 4
    for (int kb = 0; kb < 512; kb += 32) {
      bf16x8 bv = *(const bf16x8*)(hTB + (size_t)(n * 16 + fm) * SEQ + kb + fq);
      bf16x8 af = *(const bf16x8*)&tP[fm][kb + fq];
      z0 = MFMA16(af, bv, z0);
    }
    __syncthreads();   // t in Zs dead (stage 2 done for all waves)
    #pragma unroll
    for (int r = 0; r < 4; r++)
      Zs[rq + r][n * 16 + col] = f2b(z0[r]);
  } else {
    __syncthreads();
  }
  __syncthreads();

  // ---- stage 3b: O = Z @ Gt^T (16 x 96); waves 0..5, one n-frag each ------
  if (wave < 6) {
    int n = wave;
    f32x4 o0 = (f32x4){0.f, 0.f, 0.f, 0.f};
    #pragma unroll
    for (int kb = 0; kb < 96; kb += 32) {
      bf16x8 af = *(const bf16x8*)&Zs[fm][kb + fq];
      bf16x8 bv = *(const bf16x8*)(GtH + (size_t)(n * 16 + fm) * DIM + kb + fq);
      o0 = MFMA16(af, bv, o0);
    }
    #pragma unroll
    for (int r = 0; r < 4; r++) {
      int gr = b * SEQ + m0 + rq + r;
      atomicAdd(x + (size_t)gr * DIM + n * 16 + col, o0[r]);
    }
  }
}

// ====== fused MLP (8 waves): [gmid-LN] + LN + GEMM1 + GELU + GEMM2 + res ====
// grid (32) x 512 threads; each block owns 32 rows. LN epilogue:
// lnmode 1 -> hn/hnT with gamma(lngb+lngoff); lnmode 2 -> final LN to dout.
__global__ __launch_bounds__(512) void fmlp_kernel(
    float* __restrict__ X,
    const void* __restrict__ gmidb, size_t gmidoff, int useMid,
    const void* __restrict__ gmb, size_t gmoff,
    const bf16* __restrict__ w1T,   // [384][96]
    const void* __restrict__ b1b, size_t b1off,
    const bf16* __restrict__ w2T,   // [96][384]
    const void* __restrict__ b2b, size_t b2off,
    int lnmode, const void* __restrict__ lngb, size_t lngoff,
    bf16* __restrict__ hn, bf16* __restrict__ hnT, void* __restrict__ dout,
    const int* __restrict__ flagp) {
  __shared__ float X1s[32][96];   // residual basis, updated in-place by GEMM2
  __shared__ bf16 As[32][104];
  __shared__ bf16 Hs[32][392];
  int f = *flagp;
  int tid = threadIdx.x, lane = tid & 63, wave = tid >> 6;  // 0..7
  int fm = lane & 15, fq = (lane >> 4) * 8;
  int col = lane & 15, rq = (lane >> 4) * 4;
  int m0 = blockIdx.x * 32;
  const char* gm = gptr(gmb, gmoff, f);
  float gm0 = gload(gm, lane, f) + 1.f;
  float gm1 = (lane < 32) ? (gload(gm, 64 + lane, f) + 1.f) : 0.f;
  float gd0 = 1.f, gd1 = 1.f;
  if (useMid) {
    const char* gmid = gptr(gmidb, gmidoff, f);
    gd0 = gload(gmid, lane, f) + 1.f;
    gd1 = (lane < 32) ? (gload(gmid, 64 + lane, f) + 1.f) : 0.f;
  }
  for (int r = wave; r < 32; r += 8) {
    const float* xr = X + (size_t)(m0 + r) * DIM;
    float v0 = xr[lane];
    float v1 = (lane < 32) ? xr[64 + lane] : 0.f;
    if (useMid) {
      float s = v0 + v1;
      #pragma unroll
      for (int off = 32; off > 0; off >>= 1) s += __shfl_xor(s, off);
      float mu = s * (1.f / 96.f);
      float d0 = v0 - mu;
      float d1 = (lane < 32) ? (v1 - mu) : 0.f;
      float q = d0 * d0 + d1 * d1;
      #pragma unroll
      for (int off = 32; off > 0; off >>= 1) q += __shfl_xor(q, off);
      float rstd = rsqrtf(q * (1.f / 96.f) + EPSLN);
      v0 = d0 * rstd * gd0;
      v1 = (lane < 32) ? (d1 * rstd * gd1) : 0.f;
    }
    X1s[r][lane] = v0;
    if (lane < 32) X1s[r][64 + lane] = v1;
    float s = v0 + v1;
    #pragma unroll
    for (int off = 32; off > 0; off >>= 1) s += __shfl_xor(s, off);
    float mu = s * (1.f / 96.f);
    float d0 = v0 - mu;
    float d1 = (lane < 32) ? (v1 - mu) : 0.f;
    float q = d0 * d0 + d1 * d1;
    #pragma unroll
    for (int off = 32; off > 0; off >>= 1) q += __shfl_xor(q, off);
    float rstd = rsqrtf(q * (1.f / 96.f) + EPSLN);
    As[r][lane] = f2b(d0 * rstd * gm0);
    if (lane < 32) As[r][64 + lane] = f2b(d1 * rstd * gm1);
  }
  __syncthreads();

  // ---- GEMM1: [32x96] @ W1 -> [32x384]; wave = (m, 96-col chunk) ----
  int mw = wave & 1, nh = wave >> 1;     // nh in 0..3: cols [nh*96, nh*96+96)
  f32x4 acc1[6];
  #pragma unroll
  for (int j = 0; j < 6; j++) acc1[j] = (f32x4){0.f, 0.f, 0.f, 0.f};
  #pragma unroll
  for (int kb = 0; kb < 96; kb += 32) {
    bf16x8 af = *(const bf16x8*)&As[mw * 16 + fm][kb + fq];
    #pragma unroll
    for (int j = 0; j < 6; j++) {
      bf16x8 bv = *(const bf16x8*)(w1T + (size_t)(nh * 96 + j * 16 + fm) * DIM + kb + fq);
      acc1[j] = MFMA16(af, bv, acc1[j]);
    }
  }
  const char* b1p = gptr(b1b, b1off, f);
  #pragma unroll
  for (int j = 0; j < 6; j++) {
    int gn = nh * 96 + j * 16 + col;
    float bv = gload(b1p, gn, f);
    #pragma unroll
    for (int r = 0; r < 4; r++) {
      float v = acc1[j][r] + bv;
      v = 0.5f * v * (1.f + erff(v * 0.70710678118f));
      Hs[mw * 16 + rq + r][gn] = f2b(v);
    }
  }
  __syncthreads();

  // ---- GEMM2: [32x384] @ W2 -> [32x96]; waves 0..5, 2 n-frags each ----
  // Updates X1s in-place (residual + out + bias) and stores to global X.
  if (wave < 6) {
    int mA = wave & 1, nb = wave >> 1;
    f32x4 o0 = (f32x4){0.f, 0.f, 0.f, 0.f}, o1 = o0;
    #pragma unroll 4
    for (int kb = 0; kb < 384; kb += 32) {
      bf16x8 af = *(const bf16x8*)&Hs[mA * 16 + fm][kb + fq];
      bf16x8 b0 = *(const bf16x8*)(w2T + (size_t)(nb * 16 + fm) * HIDN + kb + fq);
      bf16x8 b1 = *(const bf16x8*)(w2T + (size_t)((nb + 3) * 16 + fm) * HIDN + kb + fq);
      o0 = MFMA16(af, b0, o0);
      o1 = MFMA16(af, b1, o1);
    }
    const char* b2p = gptr(b2b, b2off, f);
    float bb0 = gload(b2p, nb * 16 + col, f);
    float bb1 = gload(b2p, (nb + 3) * 16 + col, f);
    #pragma unroll
    for (int r = 0; r < 4; r++) {
      int row = mA * 16 + rq + r;
      int gmr = m0 + row;
      float nv0 = X1s[row][nb * 16 + col] + o0[r] + bb0;
      float nv1 = X1s[row][(nb + 3) * 16 + col] + o1[r] + bb1;
      X[(size_t)gmr * DIM + nb * 16 + col] = nv0;
      X[(size_t)gmr * DIM + (nb + 3) * 16 + col] = nv1;
      X1s[row][nb * 16 + col] = nv0;
      X1s[row][(nb + 3) * 16 + col] = nv1;
    }
  }
  __syncthreads();

  // ---- fused LN epilogue over this block's 32 rows (reads X1s, not X) ----
  const char* lg = gptr(lngb, lngoff, f);
  for (int r = wave; r < 32; r += 8) {
    int row = m0 + r;
    size_t base = (size_t)row * DIM;
    float v0 = X1s[r][lane];
    float v1 = (lane < 32) ? X1s[r][64 + lane] : 0.f;
    float o0, o1;
    ln_row_vals(v0, v1, lane, lg, f, o0, o1);
    if (lnmode == 1) {
      store_hn(hn, hnT, row, lane, o0, o1);
    } else {
      if (!f) {
        ((float*)dout)[base + lane] = o0;
        if (lane < 32) ((float*)dout)[base + 64 + lane] = o1;
      } else {
        ((bf16*)dout)[base + lane] = f2b(o0);
        if (lane < 32) ((bf16*)dout)[base + 64 + lane] = f2b(o1);
      }
    }
  }
}

// ---------------- host-side orchestration ----------------
extern "C" void kernel_launch(void* const* d_in, const int* in_sizes, int n_in,
                              void* d_out, int out_size, void* d_ws, size_t ws_size,
                              hipStream_t stream) {
  const void* in_x    = d_in[0];
  const void* gam_a   = d_in[1];
  const void* Wq      = d_in[2];
  const void* Wk      = d_in[3];
  const void* Wv      = d_in[4];
  const void* Wo      = d_in[5];
  const void* gam_m   = d_in[6];
  const void* W1      = d_in[7];
  const void* b1      = d_in[8];
  const void* W2      = d_in[9];
  const void* b2      = d_in[10];
  const void* gam_mid = d_in[11];
  const void* gam_fin = d_in[12];

  char* wsb = (char*)d_ws;
  size_t off = 0;
  auto carve = [&](size_t bytes) {
    char* p = wsb + off;
    off += (bytes + 255) & ~(size_t)255;
    return p;
  };
  int*   flag = (int*)carve(256);
  float* x    = (float*)carve((size_t)TOK * DIM * 4);
  bf16*  hn   = (bf16*)carve((size_t)TOK * DIM * 2);
  bf16*  hnT  = (bf16*)carve((size_t)2 * DIM * SEQ * 2);
  const size_t WSZ = (size_t)15 * DIM * INNER;   // per big weight, elements
  bf16*  woT  = (bf16*)carve(WSZ * 2);
  bf16*  w1T  = (bf16*)carve((size_t)10 * DIM * HIDN * 2);
  bf16*  w2T  = (bf16*)carve((size_t)10 * DIM * HIDN * 2);
  bf16*  Mt   = (bf16*)carve((size_t)120 * DIM * DIM * 2);
  bf16*  Gt   = (bf16*)carve((size_t)120 * DIM * DIM * 2);
  float* MtP  = (float*)carve((size_t)2 * 240 * DIM * DIM * 4);

  detect_kernel<<<dim3(1), dim3(256), 0, stream>>>(in_x, flag);

  // ---- once-per-call weight prep (3 dispatches) ----
  wtrans_all_kernel<<<dim3(6180), dim3(256), 0, stream>>>(
      Wo, W1, W2, woT, w1T, w2T, flag);
  // Mt/Gt: K-split x2, m-split x3 -> 1440 blocks of fp32 partials.
  mtgt_kernel<<<dim3(6, 1, 240), dim3(256), 0, stream>>>(
      Wq, Wk, Wv, woT, MtP, flag);
  // fused: partial-sum/convert -> Mt/Gt  +  input cast + LN0 -> x, hn, hnT
  cvtcast_kernel<<<dim3(2160 + 256), dim3(256), 0, stream>>>(
      MtP, Mt, Gt, in_x, x, hn, hnT, gam_a, flag);

  auto attn = [&](int d, int j) {
    size_t gi = ((size_t)d * 3 + j);
    fattn5_kernel<<<dim3(32, 16), dim3(512), 0, stream>>>(
        hn, hnT, Mt + gi * 8 * DIM * DIM, Gt + gi * 8 * DIM * DIM, x);
  };

  for (int d = 0; d < NDEPTH; d++) {
    bool last = (d == NDEPTH - 1);
    attn(d, 0);
    // mlp0 + fused LN(gam_a[d,1]) -> hn/hnT for attn1
    fmlp_kernel<<<dim3(32), dim3(512), 0, stream>>>(
        x, nullptr, 0, 0,
        gam_m, (size_t)(d * 2 + 0) * DIM,
        w1T + (size_t)(d * 2 + 0) * DIM * HIDN, b1, (size_t)(d * 2 + 0) * HIDN,
        w2T + (size_t)(d * 2 + 0) * DIM * HIDN, b2, (size_t)(d * 2 + 0) * DIM,
        1, gam_a, (size_t)(d * 3 + 1) * DIM, hn, hnT, nullptr, flag);
    attn(d, 1);
    ln_kernel<<<dim3(TOK / 4), dim3(256), 0, stream>>>(
        x, hn, hnT, gam_a, (size_t)(d * 3 + 2) * DIM, flag);
    attn(d, 2);
    // mlp1 (includes bare mid-LN) + fused LN: next gam_a[.,0] or final -> dout
    fmlp_kernel<<<dim3(32), dim3(512), 0, stream>>>(
        x, gam_mid, (size_t)d * DIM, 1,
        gam_m, (size_t)(d * 2 + 1) * DIM,
        w1T + (size_t)(d * 2 + 1) * DIM * HIDN, b1, (size_t)(d * 2 + 1) * HIDN,
        w2T + (size_t)(d * 2 + 1) * DIM * HIDN, b2, (size_t)(d * 2 + 1) * DIM,
        last ? 2 : 1, last ? gam_fin : gam_a,
        last ? (size_t)0 : (size_t)((d + 1) * 3) * DIM,
        hn, hnT, d_out, flag);
  }
}

// Round 10
// 581.770 us; speedup vs baseline: 1.1384x; 1.1118x over previous
//
#include <hip/hip_runtime.h>
#include <hip/hip_bf16.h>

typedef __hip_bfloat16 bf16;
typedef __attribute__((ext_vector_type(8))) short bf16x8;   // 8 bf16 = 4 VGPRs
typedef __attribute__((ext_vector_type(4))) float f32x4;

#define TOK    1024
#define DIM    96
#define HIDN   384
#define HEADS  8
#define DH     768
#define INNER  6144
#define SEQ    512
#define NDEPTH 5
#define EPSLN  1e-5f
#define QSCALE 0.125f
#define NMT    (120 * DIM * DIM)     // Mt element count (also Gt)
#define NP     (240 * DIM * DIM)     // per-ks partial plane

#define MFMA16(a, b, c) __builtin_amdgcn_mfma_f32_16x16x32_bf16((a), (b), (c), 0, 0, 0)

__device__ __forceinline__ float b2f(bf16 v) { return __bfloat162float(v); }
__device__ __forceinline__ bf16  f2b(float v) { return __float2bfloat16(v); }

// Load element i from an external input buffer: f==1 -> bf16, f==0 -> fp32.
__device__ __forceinline__ float gload(const void* p, size_t i, int f) {
  return f ? b2f(((const bf16*)p)[i]) : ((const float*)p)[i];
}
__device__ __forceinline__ const char* gptr(const void* base, size_t off, int f) {
  return (const char*)base + off * (size_t)(f ? 2 : 4);
}

// pack 8 fp32 -> 8 bf16 (two float4 registers) into a uint4
__device__ __forceinline__ uint4 pack8(float4 u0, float4 u1) {
  alignas(16) unsigned short o[8];
  bf16 t;
  t = f2b(u0.x); o[0] = *(unsigned short*)&t;
  t = f2b(u0.y); o[1] = *(unsigned short*)&t;
  t = f2b(u0.z); o[2] = *(unsigned short*)&t;
  t = f2b(u0.w); o[3] = *(unsigned short*)&t;
  t = f2b(u1.x); o[4] = *(unsigned short*)&t;
  t = f2b(u1.y); o[5] = *(unsigned short*)&t;
  t = f2b(u1.z); o[6] = *(unsigned short*)&t;
  t = f2b(u1.w); o[7] = *(unsigned short*)&t;
  return *(const uint4*)o;
}

// ---------------- dtype detector (bf16 vs fp32 external buffers) ------------
__global__ __launch_bounds__(256) void detect_kernel(const void* xraw, int* flag) {
  __shared__ int cnt[256];
  int t = threadIdx.x;
  const unsigned short* u = (const unsigned short*)xraw;
  int c = 0;
  #pragma unroll
  for (int i = 0; i < 4; i++) {
    unsigned short h = u[2 * (t * 4 + i)];
    int e = (h >> 7) & 0xFF;
    if (e >= 87 && e <= 132) c++;
  }
  cnt[t] = c;
  __syncthreads();
  for (int s = 128; s > 0; s >>= 1) {
    if (t < s) cnt[t] += cnt[t + s];
    __syncthreads();
  }
  if (t == 0) *flag = (cnt[0] > 700) ? 1 : 0;
}

// ---- weight transpose body: [bz][R][C] -> bf16 [bz][C][R] ------------------
__device__ void wtrans_body(const void* __restrict__ src, int R, int C,
                            bf16* __restrict__ dst, int bx, int by, int bz,
                            int f) {
  __shared__ float tile[32][65];
  int t = threadIdx.x;
  int c0 = bx * 64, r0 = by * 32;
  size_t bb = (size_t)bz * R * C;
  int ty = t >> 4, tx = t & 15;
  #pragma unroll
  for (int half = 0; half < 2; half++) {
    int r = r0 + ty + half * 16;
    int c = c0 + tx * 4;
    if (c < C) {
      size_t idx = bb + (size_t)r * C + c;
      float v0, v1, v2, v3;
      if (f) {
        uint2 u = *(const uint2*)((const unsigned short*)src + idx);
        v0 = __uint_as_float((u.x & 0xffffu) << 16);
        v1 = __uint_as_float(u.x & 0xffff0000u);
        v2 = __uint_as_float((u.y & 0xffffu) << 16);
        v3 = __uint_as_float(u.y & 0xffff0000u);
      } else {
        float4 v = *(const float4*)((const float*)src + idx);
        v0 = v.x; v1 = v.y; v2 = v.z; v3 = v.w;
      }
      tile[ty + half * 16][tx * 4 + 0] = v0;
      tile[ty + half * 16][tx * 4 + 1] = v1;
      tile[ty + half * 16][tx * 4 + 2] = v2;
      tile[ty + half * 16][tx * 4 + 3] = v3;
    }
  }
  __syncthreads();
  int cc = c0 + (t >> 2), rseg = (t & 3) * 8;
  if (cc < C) {
    int cs = cc - c0;
    alignas(16) unsigned short o[8];
    #pragma unroll
    for (int j = 0; j < 8; j++) {
      bf16 tv = f2b(tile[rseg + j][cs]);
      o[j] = *(unsigned short*)&tv;
    }
    *(uint4*)&dst[bb + (size_t)cc * R + r0 + rseg] = *(const uint4*)o;
  }
}

// =================== MFMA GEMM body — BT form (B is [N][K]) =================
// A/B sources may be fp32 (converted to bf16 during LDS staging) or bf16.
// Block 256 = 4 waves (2x2), TM=32. Stores raw fp32 partials to Cf.
__device__ void gemm_bt32_body(
    const void* __restrict__ A, int aF32, int lda,
    const void* __restrict__ Bt, int bF32, int ldb,
    int m0, int kbeg, int kend, int N,
    float* __restrict__ Cf, int ldc) {
  __shared__ bf16 As[32][40];
  __shared__ bf16 Bs[128][40];
  int t = threadIdx.x;
  int lane = t & 63;
  int wave = t >> 6;
  int wm = (wave >> 1) * 16, wn = (wave & 1) * 64;
  f32x4 acc[4];
  #pragma unroll
  for (int j = 0; j < 4; j++) acc[j] = (f32x4){0.f, 0.f, 0.f, 0.f};

  int arow = t >> 2, aseg = (t & 3) * 8;

  for (int kb = kbeg; kb < kend; kb += 32) {
    if (arow < 32) {
      size_t idx = (size_t)(m0 + arow) * lda + kb + aseg;
      if (aF32) {
        const float* Af = (const float*)A;
        float4 u0 = *(const float4*)(Af + idx);
        float4 u1 = *(const float4*)(Af + idx + 4);
        *(uint4*)&As[arow][aseg] = pack8(u0, u1);
      } else {
        *(uint4*)&As[arow][aseg] = *(const uint4*)((const bf16*)A + idx);
      }
    }
    #pragma unroll
    for (int i = 0; i < 2; i++) {
      int r = arow + i * 64;
      if (r < N) {
        size_t idx = (size_t)r * ldb + kb + aseg;
        if (bF32) {
          const float* Bf = (const float*)Bt;
          float4 u0 = *(const float4*)(Bf + idx);
          float4 u1 = *(const float4*)(Bf + idx + 4);
          *(uint4*)&Bs[r][aseg] = pack8(u0, u1);
        } else {
          *(uint4*)&Bs[r][aseg] = *(const uint4*)((const bf16*)Bt + idx);
        }
      } else {
        uint4 zz = {0, 0, 0, 0};
        *(uint4*)&Bs[r][aseg] = zz;
      }
    }
    __syncthreads();
    int fm = lane & 15, fq = (lane >> 4) * 8;
    bf16x8 af = *(const bf16x8*)&As[wm + fm][fq];
    bf16x8 bfv[4];
    #pragma unroll
    for (int j = 0; j < 4; j++)
      bfv[j] = *(const bf16x8*)&Bs[wn + j * 16 + fm][fq];
    #pragma unroll
    for (int j = 0; j < 4; j++)
      acc[j] = MFMA16(af, bfv[j], acc[j]);
    __syncthreads();
  }
  int col = lane & 15, rq = (lane >> 4) * 4;
  #pragma unroll
  for (int j = 0; j < 4; j++) {
    int gn = wn + j * 16 + col;
    if (gn >= N) continue;
    #pragma unroll
    for (int r = 0; r < 4; r++) {
      int gm = m0 + wm + rq + r;
      Cf[(size_t)gm * ldc + gn] = acc[j][r];
    }
  }
}

// ---- mtgt partial body: idx in [0,720) selects (z-local, ks, mt) -----------
__device__ void mtgt_body(int idx, int isM,
    const void* __restrict__ WqE, const void* __restrict__ WkE,
    const void* __restrict__ WvE, const bf16* __restrict__ woT,
    float* __restrict__ P, int f) {
  int zz = idx / 6;                // local z 0..119
  int rem = idx % 6;
  int ks = rem / 3, mt = rem % 3;
  int z = isM ? zz : (120 + zz);   // global partial plane index
  int L = zz >> 3, h = zz & 7;
  size_t wo = (size_t)L * DIM * INNER + (size_t)h * DH;
  const void* A  = isM ? (const void*)((const char*)WkE + wo * (f ? 2 : 4))
                       : (const void*)(woT + wo);
  const void* Bt = isM ? (const void*)((const char*)WqE + wo * (f ? 2 : 4))
                       : (const void*)((const char*)WvE + wo * (f ? 2 : 4));
  int aF32 = isM ? !f : 0;
  int bF32 = !f;
  float* Cf = P + ((size_t)ks * 240 + z) * DIM * DIM;
  gemm_bt32_body(A, aF32, INNER, Bt, bF32, INNER,
                 mt * 32, ks * (DH / 2), (ks + 1) * (DH / 2), DIM, Cf, DIM);
}

// ---- cvt helper: sum 2 K-split partials, scale, convert 4 elems ------------
__device__ __forceinline__ void cvt4(const float* __restrict__ P, size_t i0,
                                     float alpha, bf16* __restrict__ out) {
  float4 a = *(const float4*)(P + i0);
  float4 b = *(const float4*)(P + (size_t)NP + i0);
  alignas(8) unsigned short o[4];
  bf16 t;
  t = f2b((a.x + b.x) * alpha); o[0] = *(unsigned short*)&t;
  t = f2b((a.y + b.y) * alpha); o[1] = *(unsigned short*)&t;
  t = f2b((a.z + b.z) * alpha); o[2] = *(unsigned short*)&t;
  t = f2b((a.w + b.w) * alpha); o[3] = *(unsigned short*)&t;
  *(uint2*)out = *(const uint2*)o;
}

// ---- per-row LayerNorm helper: one wave, row of 96 (v1 valid for lane<32) --
__device__ __forceinline__ void ln_row_vals(float v0, float v1in, int lane,
    const char* g, int f, float& o0, float& o1) {
  float v1 = (lane < 32) ? v1in : 0.f;
  float s = v0 + v1;
  #pragma unroll
  for (int off = 32; off > 0; off >>= 1) s += __shfl_xor(s, off);
  float mu = s * (1.f / 96.f);
  float d0 = v0 - mu;
  float d1 = (lane < 32) ? (v1 - mu) : 0.f;
  float q = d0 * d0 + d1 * d1;
  #pragma unroll
  for (int off = 32; off > 0; off >>= 1) q += __shfl_xor(q, off);
  float rstd = rsqrtf(q * (1.f / 96.f) + EPSLN);
  o0 = d0 * rstd * (gload(g, lane, f) + 1.f);
  o1 = (lane < 32) ? (d1 * rstd * (gload(g, 64 + lane, f) + 1.f)) : 0.f;
}

__device__ __forceinline__ void store_hn(bf16* hn, bf16* hnT, int row, int lane,
                                         float o0, float o1) {
  size_t base = (size_t)row * DIM;
  bf16* hT = hnT + (size_t)(row >> 9) * DIM * SEQ;
  int ss = row & (SEQ - 1);
  hn[base + lane] = f2b(o0);
  hT[(size_t)lane * SEQ + ss] = f2b(o0);
  if (lane < 32) {
    hn[base + 64 + lane] = f2b(o1);
    hT[(size_t)(64 + lane) * SEQ + ss] = f2b(o1);
  }
}

// ==== prep1: wtrans(Wo/W1/W2) (6180 blocks) + Mt partials (720 blocks) ======
__global__ __launch_bounds__(256) void prep1_kernel(
    const void* __restrict__ Wo, const void* __restrict__ W1,
    const void* __restrict__ W2, bf16* __restrict__ woT,
    bf16* __restrict__ w1T, bf16* __restrict__ w2T,
    const void* __restrict__ WqE, const void* __restrict__ WkE,
    float* __restrict__ P, const int* __restrict__ flagp) {
  int f = *flagp;
  int b = blockIdx.x;
  if (b < 5760) {
    int bz = b / 384; int rem = b % 384;
    wtrans_body(Wo, INNER, DIM, woT, rem & 1, rem >> 1, bz, f);
  } else if (b < 5940) {
    int idx = b - 5760;
    wtrans_body(W1, DIM, HIDN, w1T, idx % 6, (idx / 6) % 3, idx / 18, f);
  } else if (b < 6180) {
    int idx = b - 5940;
    wtrans_body(W2, HIDN, DIM, w2T, idx & 1, (idx >> 1) % 12, idx / 24, f);
  } else {
    mtgt_body(b - 6180, 1, WqE, WkE, nullptr, nullptr, P, f);
  }
}

// ==== prep2: Gt partials (720 blocks) + cvt Mt (1080 blocks) ================
__global__ __launch_bounds__(256) void prep2_kernel(
    const void* __restrict__ WvE, const bf16* __restrict__ woT,
    float* __restrict__ P, bf16* __restrict__ Mt,
    const int* __restrict__ flagp) {
  int f = *flagp;
  int b = blockIdx.x;
  if (b < 720) {
    mtgt_body(b, 0, nullptr, nullptr, WvE, woT, P, f);
  } else {
    size_t i0 = ((size_t)(b - 720) * 256 + threadIdx.x) * 4;
    if (i0 < (size_t)NMT) cvt4(P, i0, QSCALE, Mt + i0);
  }
}

// ==== prep3: cvt Gt (1080 blocks) + input cast + LN0 (256 blocks) ===========
__global__ __launch_bounds__(256) void prep3_kernel(
    const float* __restrict__ P, bf16* __restrict__ Gt,
    const void* __restrict__ in_x, float* __restrict__ x,
    bf16* __restrict__ hn, bf16* __restrict__ hnT,
    const void* __restrict__ gb, const int* __restrict__ flagp) {
  int b = blockIdx.x;
  if (b < 1080) {
    size_t loc = ((size_t)b * 256 + threadIdx.x) * 4;
    if (loc < (size_t)NMT) cvt4(P, (size_t)NMT + loc, 1.f, Gt + loc);
  } else {
    int f = *flagp;
    int wave = threadIdx.x >> 6, lane = threadIdx.x & 63;
    int row = (b - 1080) * 4 + wave;
    size_t base = (size_t)row * DIM;
    float v0 = gload(in_x, base + lane, f);
    float v1 = (lane < 32) ? gload(in_x, base + 64 + lane, f) : 0.f;
    x[base + lane] = v0;
    if (lane < 32) x[base + 64 + lane] = v1;
    float o0, o1;
    ln_row_vals(v0, v1, lane, gptr(gb, 0, f), f, o0, o1);
    store_hn(hn, hnT, row, lane, o0, o1);
  }
}

// ---- standalone LN (attn -> attn transition): grid 256 x 256t --------------
__global__ __launch_bounds__(256) void ln_kernel(
    const float* __restrict__ x, bf16* __restrict__ hn, bf16* __restrict__ hnT,
    const void* __restrict__ gb, size_t goff, const int* __restrict__ flagp) {
  int f = *flagp;
  int wave = threadIdx.x >> 6, lane = threadIdx.x & 63;
  int row = blockIdx.x * 4 + wave;
  size_t base = (size_t)row * DIM;
  float v0 = x[base + lane];
  float v1 = (lane < 32) ? x[base + 64 + lane] : 0.f;
  float o0, o1;
  ln_row_vals(v0, v1, lane, gptr(gb, goff, f), f, o0, o1);
  store_hn(hn, hnT, row, lane, o0, o1);
}

// ============== fused attention v5: 16-row q-tiles, 2 blocks/CU =============
// grid (32 q-tiles, 16 z=b*8+h) x 512 threads (8 waves).
__global__ __launch_bounds__(512) void fattn5_kernel(
    const bf16* __restrict__ hn,    // [1024][96]
    const bf16* __restrict__ hnT,   // [2][96][512]
    const bf16* __restrict__ MtL,   // [8][96][96]
    const bf16* __restrict__ GtL,   // [8][96][96]
    float* __restrict__ x) {
  __shared__ bf16 tP[16][520];
  __shared__ bf16 Zs[16][104];
  __shared__ float red[2][8][16];
  int tid = threadIdx.x, lane = tid & 63, wave = tid >> 6;  // wave 0..7
  int fm = lane & 15, fq = (lane >> 4) * 8;
  int col = lane & 15, rq = (lane >> 4) * 4;
  int z = blockIdx.y, b = z >> 3, h = z & 7;
  int m0 = blockIdx.x * 16;
  const bf16* hnB = hn + (size_t)b * SEQ * DIM;
  const bf16* hTB = hnT + (size_t)b * DIM * SEQ;
  const bf16* MtH = MtL + (size_t)h * DIM * DIM;
  const bf16* GtH = GtL + (size_t)h * DIM * DIM;

  // ---- stage 1: t = hn_tile[16x96] @ Mt^T; waves 0..5, one n-frag each ----
  if (wave < 6) {
    int n = wave;
    f32x4 a0 = (f32x4){0.f, 0.f, 0.f, 0.f};
    #pragma unroll
    for (int kb = 0; kb < 96; kb += 32) {
      bf16x8 af = *(const bf16x8*)(hnB + (size_t)(m0 + fm) * DIM + kb + fq);
      bf16x8 bv = *(const bf16x8*)(MtH + (size_t)(n * 16 + fm) * DIM + kb + fq);
      a0 = MFMA16(af, bv, a0);
    }
    #pragma unroll
    for (int r = 0; r < 4; r++)
      Zs[rq + r][n * 16 + col] = f2b(a0[r]);
  }
  __syncthreads();

  // ---- stage 2: S = t @ hn^T (16 x 512); wave covers 64 cols ----
  f32x4 acc2[4];
  #pragma unroll
  for (int j = 0; j < 4; j++) acc2[j] = (f32x4){0.f, 0.f, 0.f, 0.f};
  #pragma unroll
  for (int kb = 0; kb < 96; kb += 32) {
    bf16x8 af = *(const bf16x8*)&Zs[fm][kb + fq];
    bf16x8 bv[4];
    #pragma unroll
    for (int j = 0; j < 4; j++)
      bv[j] = *(const bf16x8*)(hnB + (size_t)(wave * 64 + j * 16 + fm) * DIM + kb + fq);
    #pragma unroll
    for (int j = 0; j < 4; j++)
      acc2[j] = MFMA16(af, bv[j], acc2[j]);
  }

  // ---- softmax over 512 cols (8 wave-partials) ----
  float rmax[4];
  #pragma unroll
  for (int r = 0; r < 4; r++) {
    float m = -1e30f;
    #pragma unroll
    for (int j = 0; j < 4; j++) m = fmaxf(m, acc2[j][r]);
    rmax[r] = m;
  }
  #pragma unroll
  for (int s = 1; s < 16; s <<= 1)
    #pragma unroll
    for (int r = 0; r < 4; r++)
      rmax[r] = fmaxf(rmax[r], __shfl_xor(rmax[r], s));
  if (col == 0)
    #pragma unroll
    for (int r = 0; r < 4; r++) red[0][wave][rq + r] = rmax[r];
  __syncthreads();
  float rsum[4];
  #pragma unroll
  for (int r = 0; r < 4; r++) {
    int row = rq + r;
    float gm = red[0][0][row];
    #pragma unroll
    for (int q = 1; q < 8; q++) gm = fmaxf(gm, red[0][q][row]);
    float s = 0.f;
    #pragma unroll
    for (int j = 0; j < 4; j++) {
      float e = __expf(acc2[j][r] - gm);
      acc2[j][r] = e;
      s += e;
    }
    rsum[r] = s;
  }
  #pragma unroll
  for (int s = 1; s < 16; s <<= 1)
    #pragma unroll
    for (int r = 0; r < 4; r++)
      rsum[r] += __shfl_xor(rsum[r], s);
  if (col == 0)
    #pragma unroll
    for (int r = 0; r < 4; r++) red[1][wave][rq + r] = rsum[r];
  __syncthreads();

  // each wave writes its own normalized 64-col P chunk
  #pragma unroll
  for (int r = 0; r < 4; r++) {
    int row = rq + r;
    float tot = red[1][0][row];
    #pragma unroll
    for (int q = 1; q < 8; q++) tot += red[1][q][row];
    float inv = 1.f / tot;
    #pragma unroll
    for (int j = 0; j < 4; j++)
      tP[row][wave * 64 + j * 16 + col] = f2b(acc2[j][r] * inv);
  }
  __syncthreads();

  // ---- stage 3a: Z = P @ hnT^T (16 x 96), K = 512; waves 0..5 -------------
  if (wave < 6) {
    int n = wave;
    f32x4 z0 = (f32x4){0.f, 0.f, 0.f, 0.f};
    #pragma unroll 4
    for (int kb = 0; kb < 512; kb += 32) {
      bf16x8 bv = *(const bf16x8*)(hTB + (size_t)(n * 16 + fm) * SEQ + kb + fq);
      bf16x8 af = *(const bf16x8*)&tP[fm][kb + fq];
      z0 = MFMA16(af, bv, z0);
    }
    __syncthreads();   // t in Zs dead (stage 2 done for all waves)
    #pragma unroll
    for (int r = 0; r < 4; r++)
      Zs[rq + r][n * 16 + col] = f2b(z0[r]);
  } else {
    __syncthreads();
  }
  __syncthreads();

  // ---- stage 3b: O = Z @ Gt^T (16 x 96); waves 0..5, one n-frag each ------
  if (wave < 6) {
    int n = wave;
    f32x4 o0 = (f32x4){0.f, 0.f, 0.f, 0.f};
    #pragma unroll
    for (int kb = 0; kb < 96; kb += 32) {
      bf16x8 af = *(const bf16x8*)&Zs[fm][kb + fq];
      bf16x8 bv = *(const bf16x8*)(GtH + (size_t)(n * 16 + fm) * DIM + kb + fq);
      o0 = MFMA16(af, bv, o0);
    }
    #pragma unroll
    for (int r = 0; r < 4; r++) {
      int gr = b * SEQ + m0 + rq + r;
      atomicAdd(x + (size_t)gr * DIM + n * 16 + col, o0[r]);
    }
  }
}

// ====== fused MLP v2 (8 waves, 16-row blocks): grid (64) x 512 threads ======
// [gmid-LN] + LN + GEMM1 + GELU + GEMM2 + residual; LN epilogue:
// lnmode 1 -> hn/hnT with gamma(lngb+lngoff); lnmode 2 -> final LN to dout.
__global__ __launch_bounds__(512) void fmlp_kernel(
    float* __restrict__ X,
    const void* __restrict__ gmidb, size_t gmidoff, int useMid,
    const void* __restrict__ gmb, size_t gmoff,
    const bf16* __restrict__ w1T,   // [384][96]
    const void* __restrict__ b1b, size_t b1off,
    const bf16* __restrict__ w2T,   // [96][384]
    const void* __restrict__ b2b, size_t b2off,
    int lnmode, const void* __restrict__ lngb, size_t lngoff,
    bf16* __restrict__ hn, bf16* __restrict__ hnT, void* __restrict__ dout,
    const int* __restrict__ flagp) {
  __shared__ float X1s[16][96];   // residual basis, updated in-place by GEMM2
  __shared__ bf16 As[16][104];
  __shared__ bf16 Hs[16][392];
  int f = *flagp;
  int tid = threadIdx.x, lane = tid & 63, wave = tid >> 6;  // 0..7
  int fm = lane & 15, fq = (lane >> 4) * 8;
  int col = lane & 15, rq = (lane >> 4) * 4;
  int m0 = blockIdx.x * 16;
  const char* gm = gptr(gmb, gmoff, f);
  float gm0 = gload(gm, lane, f) + 1.f;
  float gm1 = (lane < 32) ? (gload(gm, 64 + lane, f) + 1.f) : 0.f;
  float gd0 = 1.f, gd1 = 1.f;
  if (useMid) {
    const char* gmid = gptr(gmidb, gmidoff, f);
    gd0 = gload(gmid, lane, f) + 1.f;
    gd1 = (lane < 32) ? (gload(gmid, 64 + lane, f) + 1.f) : 0.f;
  }
  for (int r = wave; r < 16; r += 8) {
    const float* xr = X + (size_t)(m0 + r) * DIM;
    float v0 = xr[lane];
    float v1 = (lane < 32) ? xr[64 + lane] : 0.f;
    if (useMid) {
      float s = v0 + v1;
      #pragma unroll
      for (int off = 32; off > 0; off >>= 1) s += __shfl_xor(s, off);
      float mu = s * (1.f / 96.f);
      float d0 = v0 - mu;
      float d1 = (lane < 32) ? (v1 - mu) : 0.f;
      float q = d0 * d0 + d1 * d1;
      #pragma unroll
      for (int off = 32; off > 0; off >>= 1) q += __shfl_xor(q, off);
      float rstd = rsqrtf(q * (1.f / 96.f) + EPSLN);
      v0 = d0 * rstd * gd0;
      v1 = (lane < 32) ? (d1 * rstd * gd1) : 0.f;
    }
    X1s[r][lane] = v0;
    if (lane < 32) X1s[r][64 + lane] = v1;
    float s = v0 + v1;
    #pragma unroll
    for (int off = 32; off > 0; off >>= 1) s += __shfl_xor(s, off);
    float mu = s * (1.f / 96.f);
    float d0 = v0 - mu;
    float d1 = (lane < 32) ? (v1 - mu) : 0.f;
    float q = d0 * d0 + d1 * d1;
    #pragma unroll
    for (int off = 32; off > 0; off >>= 1) q += __shfl_xor(q, off);
    float rstd = rsqrtf(q * (1.f / 96.f) + EPSLN);
    As[r][lane] = f2b(d0 * rstd * gm0);
    if (lane < 32) As[r][64 + lane] = f2b(d1 * rstd * gm1);
  }
  __syncthreads();

  // ---- GEMM1: [16x96] @ W1 -> [16x384]; wave covers cols [wave*48, +48) ----
  f32x4 acc1[3];
  #pragma unroll
  for (int j = 0; j < 3; j++) acc1[j] = (f32x4){0.f, 0.f, 0.f, 0.f};
  #pragma unroll
  for (int kb = 0; kb < 96; kb += 32) {
    bf16x8 af = *(const bf16x8*)&As[fm][kb + fq];
    #pragma unroll
    for (int j = 0; j < 3; j++) {
      bf16x8 bv = *(const bf16x8*)(w1T + (size_t)((wave * 3 + j) * 16 + fm) * DIM + kb + fq);
      acc1[j] = MFMA16(af, bv, acc1[j]);
    }
  }
  const char* b1p = gptr(b1b, b1off, f);
  #pragma unroll
  for (int j = 0; j < 3; j++) {
    int gn = (wave * 3 + j) * 16 + col;
    float bv = gload(b1p, gn, f);
    #pragma unroll
    for (int r = 0; r < 4; r++) {
      float v = acc1[j][r] + bv;
      v = 0.5f * v * (1.f + erff(v * 0.70710678118f));
      Hs[rq + r][gn] = f2b(v);
    }
  }
  __syncthreads();

  // ---- GEMM2: [16x384] @ W2 -> [16x96]; waves 0..5, one 16-col frag each ---
  if (wave < 6) {
    int n = wave;
    f32x4 o0 = (f32x4){0.f, 0.f, 0.f, 0.f};
    #pragma unroll 4
    for (int kb = 0; kb < 384; kb += 32) {
      bf16x8 af = *(const bf16x8*)&Hs[fm][kb + fq];
      bf16x8 bv = *(const bf16x8*)(w2T + (size_t)(n * 16 + fm) * HIDN + kb + fq);
      o0 = MFMA16(af, bv, o0);
    }
    const char* b2p = gptr(b2b, b2off, f);
    float bb0 = gload(b2p, n * 16 + col, f);
    #pragma unroll
    for (int r = 0; r < 4; r++) {
      int row = rq + r;
      int gmr = m0 + row;
      float nv0 = X1s[row][n * 16 + col] + o0[r] + bb0;
      X[(size_t)gmr * DIM + n * 16 + col] = nv0;
      X1s[row][n * 16 + col] = nv0;
    }
  }
  __syncthreads();

  // ---- fused LN epilogue over this block's 16 rows (reads X1s, not X) ----
  const char* lg = gptr(lngb, lngoff, f);
  for (int r = wave; r < 16; r += 8) {
    int row = m0 + r;
    size_t base = (size_t)row * DIM;
    float v0 = X1s[r][lane];
    float v1 = (lane < 32) ? X1s[r][64 + lane] : 0.f;
    float o0, o1;
    ln_row_vals(v0, v1, lane, lg, f, o0, o1);
    if (lnmode == 1) {
      store_hn(hn, hnT, row, lane, o0, o1);
    } else {
      if (!f) {
        ((float*)dout)[base + lane] = o0;
        if (lane < 32) ((float*)dout)[base + 64 + lane] = o1;
      } else {
        ((bf16*)dout)[base + lane] = f2b(o0);
        if (lane < 32) ((bf16*)dout)[base + 64 + lane] = f2b(o1);
      }
    }
  }
}

// ---------------- host-side orchestration ----------------
extern "C" void kernel_launch(void* const* d_in, const int* in_sizes, int n_in,
                              void* d_out, int out_size, void* d_ws, size_t ws_size,
                              hipStream_t stream) {
  const void* in_x    = d_in[0];
  const void* gam_a   = d_in[1];
  const void* Wq      = d_in[2];
  const void* Wk      = d_in[3];
  const void* Wv      = d_in[4];
  const void* Wo      = d_in[5];
  const void* gam_m   = d_in[6];
  const void* W1      = d_in[7];
  const void* b1      = d_in[8];
  const void* W2      = d_in[9];
  const void* b2      = d_in[10];
  const void* gam_mid = d_in[11];
  const void* gam_fin = d_in[12];

  char* wsb = (char*)d_ws;
  size_t off = 0;
  auto carve = [&](size_t bytes) {
    char* p = wsb + off;
    off += (bytes + 255) & ~(size_t)255;
    return p;
  };
  int*   flag = (int*)carve(256);
  float* x    = (float*)carve((size_t)TOK * DIM * 4);
  bf16*  hn   = (bf16*)carve((size_t)TOK * DIM * 2);
  bf16*  hnT  = (bf16*)carve((size_t)2 * DIM * SEQ * 2);
  const size_t WSZ = (size_t)15 * DIM * INNER;   // per big weight, elements
  bf16*  woT  = (bf16*)carve(WSZ * 2);
  bf16*  w1T  = (bf16*)carve((size_t)10 * DIM * HIDN * 2);
  bf16*  w2T  = (bf16*)carve((size_t)10 * DIM * HIDN * 2);
  bf16*  Mt   = (bf16*)carve((size_t)NMT * 2);
  bf16*  Gt   = (bf16*)carve((size_t)NMT * 2);
  float* MtP  = (float*)carve((size_t)2 * NP * 4);

  detect_kernel<<<dim3(1), dim3(256), 0, stream>>>(in_x, flag);

  // ---- prep: 3 fused dispatches ----
  prep1_kernel<<<dim3(6900), dim3(256), 0, stream>>>(
      Wo, W1, W2, woT, w1T, w2T, Wq, Wk, MtP, flag);
  prep2_kernel<<<dim3(1800), dim3(256), 0, stream>>>(
      Wv, woT, MtP, Mt, flag);
  prep3_kernel<<<dim3(1336), dim3(256), 0, stream>>>(
      MtP, Gt, in_x, x, hn, hnT, gam_a, flag);

  auto attn = [&](int d, int j) {
    size_t gi = ((size_t)d * 3 + j);
    fattn5_kernel<<<dim3(32, 16), dim3(512), 0, stream>>>(
        hn, hnT, Mt + gi * 8 * DIM * DIM, Gt + gi * 8 * DIM * DIM, x);
  };

  for (int d = 0; d < NDEPTH; d++) {
    bool last = (d == NDEPTH - 1);
    attn(d, 0);
    // mlp0 + fused LN(gam_a[d,1]) -> hn/hnT for attn1
    fmlp_kernel<<<dim3(64), dim3(512), 0, stream>>>(
        x, nullptr, 0, 0,
        gam_m, (size_t)(d * 2 + 0) * DIM,
        w1T + (size_t)(d * 2 + 0) * DIM * HIDN, b1, (size_t)(d * 2 + 0) * HIDN,
        w2T + (size_t)(d * 2 + 0) * DIM * HIDN, b2, (size_t)(d * 2 + 0) * DIM,
        1, gam_a, (size_t)(d * 3 + 1) * DIM, hn, hnT, nullptr, flag);
    attn(d, 1);
    ln_kernel<<<dim3(TOK / 4), dim3(256), 0, stream>>>(
        x, hn, hnT, gam_a, (size_t)(d * 3 + 2) * DIM, flag);
    attn(d, 2);
    // mlp1 (includes bare mid-LN) + fused LN: next gam_a[.,0] or final -> dout
    fmlp_kernel<<<dim3(64), dim3(512), 0, stream>>>(
        x, gam_mid, (size_t)d * DIM, 1,
        gam_m, (size_t)(d * 2 + 1) * DIM,
        w1T + (size_t)(d * 2 + 1) * DIM * HIDN, b1, (size_t)(d * 2 + 1) * HIDN,
        w2T + (size_t)(d * 2 + 1) * DIM * HIDN, b2, (size_t)(d * 2 + 1) * DIM,
        last ? 2 : 1, last ? gam_fin : gam_a,
        last ? (size_t)0 : (size_t)((d + 1) * 3) * DIM,
        hn, hnT, d_out, flag);
  }
}